// Round 5
// baseline (2069.647 us; speedup 1.0000x reference)
//
#include <hip/hip_runtime.h>

typedef unsigned short ushort_t;
typedef unsigned long long u64_t;
typedef __attribute__((ext_vector_type(8))) short short8;
typedef __attribute__((ext_vector_type(4))) float floatx4;

#define B_ 256
#define T_ 128
#define E_ 300
#define H_ 512
#define NE_ 127   // T-1 reduce events
#define NT_ 255   // 2T-1 transitions
#define SLH_ 260  // slot_h slots per row (256 live + dump + pad)
#define SLC_ 130  // slot_c slots per row (128 live + dump + pad)
#define ZCODE_ 1023
#define PREVF_ 0x10000

__device__ inline ushort_t f2bf(float f){
  unsigned u = __builtin_bit_cast(unsigned, f);
  unsigned r = u + 0x7FFFu + ((u >> 16) & 1u);
  return (ushort_t)(r >> 16);
}
__device__ inline float bf2f(ushort_t h){
  unsigned u = ((unsigned)h) << 16;
  return __builtin_bit_cast(float, u);
}
__device__ inline float sigm(float x){ return 1.0f / (1.0f + __expf(-x)); }
// exp-based tanh: exact in the tails, ~ulp-level f32 error (<< bf16 noise).
// Saves the branchy libm tanhf on wave0's serial epilogue path.
__device__ inline float ftanh(float x){
  float e = __expf(2.0f * x);
  return 1.0f - 2.0f / (e + 1.0f);
}

// Agent-scope relaxed (sc0 sc1) ops: bypass stale L1/L2, served by L3.
__device__ inline short8 load_a_coh(const ushort_t* p){
  union { u64_t q[2]; short8 v; } u;
  u.q[0] = __hip_atomic_load((u64_t*)p,       __ATOMIC_RELAXED, __HIP_MEMORY_SCOPE_AGENT);
  u.q[1] = __hip_atomic_load((u64_t*)(p + 4), __ATOMIC_RELAXED, __HIP_MEMORY_SCOPE_AGENT);
  return u.v;
}
__device__ inline void store_h_coh(ushort_t* p, ushort_t v){
  __hip_atomic_store(p, v, __ATOMIC_RELAXED, __HIP_MEMORY_SCOPE_AGENT);
}

// ---------------------------------------------------------------------------
// x (fp32, rows of 300) -> xb (bf16, rows padded to 320, pad = 0)
// ---------------------------------------------------------------------------
__global__ __launch_bounds__(256) void xcast_kernel(const float* __restrict__ x,
    ushort_t* __restrict__ xb){
  int t = blockIdx.x * 256 + threadIdx.x;
  if (t >= (B_ * T_) * 40) return;
  int row = t / 40, k8 = (t % 40) * 8;
  const float* src = x + (size_t)row * E_;
  short8 v;
  #pragma unroll
  for (int j = 0; j < 8; ++j){
    int k = k8 + j;
    v[j] = (k < E_) ? (short)f2bf(src[k]) : (short)0;
  }
  *(short8*)(xb + (size_t)row * 320 + k8) = v;
}

// ---------------------------------------------------------------------------
// Pack a KxN row-major fp32 weight into MFMA B-fragment order (bf16).
// ---------------------------------------------------------------------------
__global__ __launch_bounds__(256) void pack_w_kernel(const float* __restrict__ W,
    ushort_t* __restrict__ dst, int K, int N, int NS, int total){
  int t = blockIdx.x * 256 + threadIdx.x;
  if (t >= total) return;
  int L = t & 63;
  int s = (t >> 6) % NS;
  int ct = t / (64 * NS);
  int n = ct * 16 + (L & 15);
  int kbase = s * 32 + ((L >> 4) << 3);
  short8 pack;
  #pragma unroll
  for (int j = 0; j < 8; ++j){
    int k = kbase + j;
    pack[j] = (k < K) ? (short)f2bf(W[(size_t)k * N + n]) : (short)0;
  }
  *(short8*)(dst + (size_t)t * 8) = pack;
}

// ---------------------------------------------------------------------------
// Stack machine with SLOT-RECYCLED storage. Codes (low 10 bits):
//   [0,128) leaf | [256,512) node at phys h-slot (c-slot = phys>>1) | 1023 zeros
// PREVF_: child is the previous event's node (c register-carried).
// ---------------------------------------------------------------------------
__global__ void sched_kernel(const int* __restrict__ trans, int* __restrict__ lsel,
    int* __restrict__ rsel, int* __restrict__ wph, int* __restrict__ rootsel){
  __shared__ int stk[32 * 128];    // value code
  __shared__ int stkid[32 * 128];  // node id (T_+e) or leaf idx
  int tid = threadIdx.x;           // 0..31
  int b0 = blockIdx.x * 32;
  int b = b0 + tid;
  for (int i = 0; i < 128; ++i){ stk[tid * 128 + i] = ZCODE_; stkid[tid * 128 + i] = -1; }
  u64_t tog0 = 0, tog1 = 0;
  int sp = 0, bp = T_, e = 0;
  for (int t = 0; t < NT_; ++t){
    int tr = trans[t * B_ + b];
    if (tr == 0){
      int pos = sp; if (pos < 0) pos = 0; if (pos > 127) pos = 127;
      stk[tid * 128 + pos] = bp - 1;
      stkid[tid * 128 + pos] = bp - 1;
      sp += 1; bp -= 1;
    } else {
      int i2 = sp - 2; if (i2 < 0) i2 = 0; if (i2 > 127) i2 = 127;
      int i1 = sp - 1; if (i1 < 0) i1 = 0; if (i1 > 127) i1 = 127;
      if (e < NE_){
        int lc = stk[tid * 128 + i2], rc = stk[tid * 128 + i1];
        int lid = stkid[tid * 128 + i2], rid = stkid[tid * 128 + i1];
        int previd = T_ + e - 1;
        lsel[e * B_ + b] = lc | ((e > 0 && lid == previd) ? PREVF_ : 0);
        rsel[e * B_ + b] = rc | ((e > 0 && rid == previd) ? PREVF_ : 0);
        int pos = i2;
        unsigned ob;
        if (pos < 64){ ob = (unsigned)((tog0 >> pos) & 1); tog0 ^= (1ull << pos); }
        else         { ob = (unsigned)((tog1 >> (pos - 64)) & 1); tog1 ^= (1ull << (pos - 64)); }
        int phys = pos * 2 + (int)(ob ^ 1u);
        wph[e * B_ + b] = phys;
        stk[tid * 128 + pos] = 256 + phys;
        stkid[tid * 128 + pos] = T_ + e;
      }
      e += 1; sp -= 1;
    }
  }
  for (int k = e; k < NE_; ++k){
    lsel[k * B_ + b] = ZCODE_; rsel[k * B_ + b] = ZCODE_;
    wph[k * B_ + b] = 256;     // dump slot — never aliases live slots
  }
  int ip = sp - 1; if (ip < 0) ip = 0; if (ip > 127) ip = 127;
  rootsel[b] = stk[tid * 128 + ip];
}

// ---------------------------------------------------------------------------
// Leaf phase from pre-cast bf16 x (padded K=320). WG = 4 waves x 16 rows =
// 64 rows, 128 cols (8 col-tiles) for both weights. Grid (512, 4).
// ---------------------------------------------------------------------------
__global__ __launch_bounds__(256) void leaf_kernel(const ushort_t* __restrict__ xb,
    const ushort_t* __restrict__ WpP, const ushort_t* __restrict__ WgP,
    const float* __restrict__ b_proj, const float* __restrict__ b_gate,
    ushort_t* __restrict__ leaf_h, ushort_t* __restrict__ leaf_c){
  int wave = threadIdx.x >> 6, lane = threadIdx.x & 63;
  int r0 = blockIdx.x * 64 + wave * 16;
  int cbase = blockIdx.y * 8;
  int arow = r0 + (lane & 15);
  int klane = (lane >> 4) << 3;
  const ushort_t* xrow = xb + (size_t)arow * 320;
  floatx4 accP[8], accG[8];
  #pragma unroll
  for (int i = 0; i < 8; ++i){ accP[i] = (floatx4){0,0,0,0}; accG[i] = (floatx4){0,0,0,0}; }
  #pragma unroll
  for (int s = 0; s < 10; ++s){
    short8 a = *(const short8*)(xrow + s * 32 + klane);
    #pragma unroll
    for (int cc = 0; cc < 8; ++cc){
      short8 bp = *(const short8*)(WpP + (((size_t)(cbase + cc) * 10 + s) * 64 + lane) * 8);
      accP[cc] = __builtin_amdgcn_mfma_f32_16x16x32_bf16(a, bp, accP[cc], 0, 0, 0);
      short8 bg = *(const short8*)(WgP + (((size_t)(cbase + cc) * 10 + s) * 64 + lane) * 8);
      accG[cc] = __builtin_amdgcn_mfma_f32_16x16x32_bf16(a, bg, accG[cc], 0, 0, 0);
    }
  }
  int rbase = r0 + ((lane >> 4) << 2);
  #pragma unroll
  for (int cc = 0; cc < 8; ++cc){
    int col = (cbase + cc) * 16 + (lane & 15);
    float bp = b_proj[col], bg = b_gate[col];
    #pragma unroll
    for (int r = 0; r < 4; ++r){
      int row = rbase + r;
      float cv = accP[cc][r] + bp;
      float hv = sigm(accG[cc][r] + bg) * ftanh(cv);
      size_t o = (size_t)row * H_ + col;
      leaf_c[o] = f2bf(cv);
      leaf_h[o] = f2bf(hv);
    }
  }
}

// ---------------------------------------------------------------------------
// Persistent chain, R12 = R8 protocol VERBATIM (harness-proven at 2022 us:
// agent-scope flags on 32 distinct 128B lines, two-barrier structure, wave0
// polls, h handoff via agent-scope sc0 sc1 ops). Only delta vs R8: the
// epilogue's tanhf -> ftanh (exp-based). All R9-R11 sc0/probe machinery
// reverted after 4 consecutive container failures with no counters — this
// re-establishes the known-good baseline and banks the safe transcendental
// win; L2-routing will be re-attempted only with fresh counter evidence.
// ---------------------------------------------------------------------------
__global__ __launch_bounds__(256, 1) void chain_kernel(
    const ushort_t* __restrict__ WrP, const float* __restrict__ b_reduce,
    const ushort_t* __restrict__ leaf_h, const ushort_t* __restrict__ leaf_c,
    ushort_t* __restrict__ slot_h, float* __restrict__ slot_c,
    const int* __restrict__ lsel, const int* __restrict__ rsel,
    const int* __restrict__ wph, const ushort_t* __restrict__ zbuf,
    unsigned* __restrict__ gflags){
  __shared__ floatx4 part[3][2][5][64];   // [kq-1][rt][g][lane] — conflict-free
  const int bid  = blockIdx.x;
  const int cth  = bid >> 3;
  const int rg   = bid & 7;
  const int kq   = threadIdx.x >> 6;     // wave = K-quarter
  const int lane = threadIdx.x & 63;
  const int m16  = lane & 15;
  const int klane = (lane >> 4) << 3;
  const int colh = cth * 16 + m16;
  const int row0 = rg * 32;
  float bias[5];
  if (kq == 0){
    #pragma unroll
    for (int g = 0; g < 5; ++g) bias[g] = b_reduce[g * H_ + colh];
  }
  const int* ssel = (kq < 2) ? lsel : rsel;    // kq 0,1 = left child half
  const int kcolbase = (kq & 1) * 256;         // col offset within child h
  unsigned* myflag  = gflags + ((unsigned)(rg * 32 + cth) << 5);       // 128B stride
  unsigned* pollptr = gflags + ((unsigned)(rg * 32 + (lane & 31)) << 5);
  float creg[2][4];                            // c written last event (wave 0)
  #pragma unroll
  for (int rt = 0; rt < 2; ++rt)
    #pragma unroll
    for (int r = 0; r < 4; ++r) creg[rt][r] = 0.0f;

  #pragma unroll 1
  for (int e = 0; e < NE_; ++e){
    // ---- child codes ----
    int code[2];
    const ushort_t* leafp[2];
    #pragma unroll
    for (int rt = 0; rt < 2; ++rt){
      int row = row0 + rt * 16 + m16;
      code[rt] = ssel[e * B_ + row] & 0x3FF;
      leafp[rt] = (code[rt] < 128) ? leaf_h + ((size_t)row * T_ + code[rt]) * H_ + kcolbase
                                   : zbuf;
    }

    // ---- W fragments: load + pin in regs BEFORE the wait (L2-hit) ----
    short8 Wreg[5][8];
    #pragma unroll
    for (int g = 0; g < 5; ++g)
      #pragma unroll
      for (int s = 0; s < 8; ++s)
        Wreg[g][s] = *(const short8*)(WrP + (((size_t)(g * 32 + cth) * 32 + kq * 8 + s) * 64 + lane) * 8);
    #pragma unroll
    for (int g = 0; g < 5; ++g)
      asm volatile("" : "+v"(Wreg[g][0]), "+v"(Wreg[g][1]), "+v"(Wreg[g][2]),
                        "+v"(Wreg[g][3]), "+v"(Wreg[g][4]), "+v"(Wreg[g][5]),
                        "+v"(Wreg[g][6]), "+v"(Wreg[g][7]));

    // ---- leaf-child A prefetch (independent of previous event) ----
    short8 Ab[2][8];
    #pragma unroll
    for (int rt = 0; rt < 2; ++rt){
      if (code[rt] < 256 || code[rt] >= 512){
        #pragma unroll
        for (int s = 0; s < 8; ++s) Ab[rt][s] = *(const short8*)(leafp[rt] + s * 32 + klane);
      }
    }

    // ---- wave 0: prefetch leaf c operands ----
    float cl[2][4], cr[2][4];
    int lsv[2][4], rsv[2][4];
    if (kq == 0){
      #pragma unroll
      for (int rt = 0; rt < 2; ++rt){
        int rbase = row0 + rt * 16 + ((lane >> 4) << 2);
        #pragma unroll
        for (int r = 0; r < 4; ++r){
          const int bb = rbase + r;
          const int ls = lsel[e * B_ + bb], rs = rsel[e * B_ + bb];
          lsv[rt][r] = ls; rsv[rt][r] = rs;
          int lc = ls & 0x3FF, rc = rs & 0x3FF;
          cl[rt][r] = (!(ls & PREVF_) && lc < 128) ? bf2f(leaf_c[((size_t)bb * T_ + lc) * H_ + colh]) : 0.0f;
          cr[rt][r] = (!(rs & PREVF_) && rc < 128) ? bf2f(leaf_c[((size_t)bb * T_ + rc) * H_ + colh]) : 0.0f;
        }
      }
    }

    // ---- wait: wave 0 gathers 32 distinct flag lines; S1 releases all ----
    if (kq == 0 && e > 0){
      const unsigned tgt = (unsigned)e;
      for (;;){
        unsigned v = __hip_atomic_load(pollptr, __ATOMIC_RELAXED, __HIP_MEMORY_SCOPE_AGENT);
        if (__all(v >= tgt)) break;
        __builtin_amdgcn_s_sleep(0);
      }
    }
    __syncthreads();   // S1: release; also LDS WAR guard for `part`

    // ---- node-child A loads (coherent, L3) ----
    #pragma unroll
    for (int rt = 0; rt < 2; ++rt){
      if (code[rt] >= 256 && code[rt] < 512){
        int row = row0 + rt * 16 + m16;
        const ushort_t* p = slot_h + ((size_t)row * SLH_ + (code[rt] - 256)) * H_ + kcolbase;
        #pragma unroll
        for (int s = 0; s < 8; ++s) Ab[rt][s] = load_a_coh(p + s * 32 + klane);
      }
    }

    // ---- wave 0: remaining c operands (PREVF regs / WG-private slot_c) ----
    if (kq == 0){
      #pragma unroll
      for (int rt = 0; rt < 2; ++rt){
        int rbase = row0 + rt * 16 + ((lane >> 4) << 2);
        #pragma unroll
        for (int r = 0; r < 4; ++r){
          const int bb = rbase + r;
          const int ls = lsv[rt][r], rs = rsv[rt][r];
          int lc = ls & 0x3FF, rc = rs & 0x3FF;
          if (ls & PREVF_) cl[rt][r] = creg[rt][r];
          else if (lc >= 256 && lc < 512) cl[rt][r] = slot_c[((size_t)bb * SLC_ + ((lc - 256) >> 1)) * H_ + colh];
          if (rs & PREVF_) cr[rt][r] = creg[rt][r];
          else if (rc >= 256 && rc < 512) cr[rt][r] = slot_c[((size_t)bb * SLC_ + ((rc - 256) >> 1)) * H_ + colh];
        }
      }
    }

    // ---- MFMA: B from pinned registers ----
    floatx4 acc[2][5];
    #pragma unroll
    for (int rt = 0; rt < 2; ++rt)
      #pragma unroll
      for (int g = 0; g < 5; ++g) acc[rt][g] = (floatx4){0,0,0,0};
    #pragma unroll
    for (int s = 0; s < 8; ++s){
      #pragma unroll
      for (int g = 0; g < 5; ++g){
        acc[0][g] = __builtin_amdgcn_mfma_f32_16x16x32_bf16(Ab[0][s], Wreg[g][s], acc[0][g], 0, 0, 0);
        acc[1][g] = __builtin_amdgcn_mfma_f32_16x16x32_bf16(Ab[1][s], Wreg[g][s], acc[1][g], 0, 0, 0);
      }
    }
    if (kq != 0){
      #pragma unroll
      for (int rt = 0; rt < 2; ++rt)
        #pragma unroll
        for (int g = 0; g < 5; ++g)
          part[kq - 1][rt][g][lane] = acc[rt][g];
    }
    __syncthreads();   // S2: partials visible to wave 0
    if (kq == 0){
      #pragma unroll
      for (int rt = 0; rt < 2; ++rt)
        #pragma unroll
        for (int g = 0; g < 5; ++g){
          floatx4 p0 = part[0][rt][g][lane];
          floatx4 p1 = part[1][rt][g][lane];
          floatx4 p2 = part[2][rt][g][lane];
          #pragma unroll
          for (int r = 0; r < 4; ++r) acc[rt][g][r] += p0[r] + p1[r] + p2[r];
        }
      #pragma unroll
      for (int rt = 0; rt < 2; ++rt){
        int rbase = row0 + rt * 16 + ((lane >> 4) << 2);
        #pragma unroll
        for (int r = 0; r < 4; ++r){
          const int bb = rbase + r;
          float cn = sigm(acc[rt][1][r] + bias[1]) * cl[rt][r]
                   + sigm(acc[rt][2][r] + bias[2]) * cr[rt][r]
                   + sigm(acc[rt][0][r] + bias[0]) * ftanh(acc[rt][3][r] + bias[3]);
          float hn = sigm(acc[rt][4][r] + bias[4]) * ftanh(cn);
          creg[rt][r] = cn;
          const int w = wph[e * B_ + bb];
          slot_c[((size_t)bb * SLC_ + (w >> 1)) * H_ + colh] = cn;   // WG-private
          store_h_coh(slot_h + ((size_t)bb * SLH_ + w) * H_ + colh, f2bf(hn));
        }
      }
      asm volatile("s_waitcnt vmcnt(0)" ::: "memory");   // drain h stores
      if (threadIdx.x == 0)
        __hip_atomic_store(myflag, (unsigned)(e + 1),
                           __ATOMIC_RELAXED, __HIP_MEMORY_SCOPE_AGENT);
    }
  }
}

// Final: out[b][j] = h of root (leaf / node slot / zeros). Covers every row.
__global__ __launch_bounds__(256) void final_kernel(const int* __restrict__ rootsel,
    const ushort_t* __restrict__ leaf_h, const ushort_t* __restrict__ slot_h,
    float* __restrict__ out){
  int i = blockIdx.x * 256 + threadIdx.x;
  if (i >= B_ * H_) return;
  int b = i >> 9, j = i & (H_ - 1);
  int code = rootsel[b] & 0x3FF;
  float v = 0.0f;
  if (code < 128)      v = bf2f(leaf_h[((size_t)b * T_ + code) * H_ + j]);
  else if (code < 512) v = bf2f(slot_h[((size_t)b * SLH_ + (code - 256)) * H_ + j]);
  out[i] = v;
}

extern "C" void kernel_launch(void* const* d_in, const int* in_sizes, int n_in,
                              void* d_out, int out_size, void* d_ws, size_t ws_size,
                              hipStream_t stream){
  const float* x        = (const float*)d_in[0];
  const float* W_proj   = (const float*)d_in[1];
  const float* b_proj   = (const float*)d_in[2];
  const float* W_gate   = (const float*)d_in[3];
  const float* b_gate   = (const float*)d_in[4];
  const float* W_reduce = (const float*)d_in[5];
  const float* b_reduce = (const float*)d_in[6];
  const int*   trans    = (const int*)d_in[7];
  float* out = (float*)d_out;

  char* ws = (char*)d_ws;
  size_t o = 0;
  ushort_t* WpP    = (ushort_t*)(ws + o); o += (size_t)32*10*64*8*2;    // 0.33 MB
  ushort_t* WgP    = (ushort_t*)(ws + o); o += (size_t)32*10*64*8*2;
  ushort_t* WrP    = (ushort_t*)(ws + o); o += (size_t)160*32*64*8*2;   // 5.24 MB
  ushort_t* leaf_h = (ushort_t*)(ws + o); o += (size_t)B_*T_*H_*2;      // 33.5 MB
  ushort_t* leaf_c = (ushort_t*)(ws + o); o += (size_t)B_*T_*H_*2;      // 33.5 MB
  ushort_t* slot_h = (ushort_t*)(ws + o); o += (size_t)B_*SLH_*H_*2;    // 68.2 MB
  float*    slot_c = (float*)(ws + o);    o += (size_t)B_*SLC_*H_*4;    // 68.2 MB
  int* lsel    = (int*)(ws + o); o += (size_t)NE_*B_*4;
  int* rsel    = (int*)(ws + o); o += (size_t)NE_*B_*4;
  int* wph     = (int*)(ws + o); o += (size_t)NE_*B_*4;
  int* rootsel = (int*)(ws + o); o += (size_t)B_*4;
  unsigned* gflags = (unsigned*)(ws + o); o += (size_t)8 * 32 * 128;  // 1 line per (rg,cth)
  ushort_t* zbuf = (ushort_t*)(ws + o); o += 2048;
  // xb (bf16 x, padded to K=320, 21 MB) overlays slot_c: xb is only read
  // before chain_kernel; slot_c is only accessed during/after it.
  ushort_t* xb = (ushort_t*)slot_c;
  (void)ws_size; (void)in_sizes; (void)n_in; (void)out_size;

  hipMemsetAsync(gflags, 0, (size_t)8 * 32 * 128, stream);
  hipMemsetAsync(zbuf, 0, 2048, stream);
  xcast_kernel<<<((B_*T_)*40 + 255)/256, 256, 0, stream>>>(x, xb);
  pack_w_kernel<<<(32*10*64 + 255)/256, 256, 0, stream>>>(W_proj, WpP, 300, 512, 10, 32*10*64);
  pack_w_kernel<<<(32*10*64 + 255)/256, 256, 0, stream>>>(W_gate, WgP, 300, 512, 10, 32*10*64);
  pack_w_kernel<<<(160*32*64 + 255)/256, 256, 0, stream>>>(W_reduce, WrP, 1024, 2560, 32, 160*32*64);
  sched_kernel<<<8, 32, 0, stream>>>(trans, lsel, rsel, wph, rootsel);
  leaf_kernel<<<dim3(512, 4), 256, 0, stream>>>(xb, WpP, WgP, b_proj, b_gate, leaf_h, leaf_c);
  chain_kernel<<<256, 256, 0, stream>>>(WrP, b_reduce, leaf_h, leaf_c, slot_h, slot_c,
                                        lsel, rsel, wph, zbuf, gflags);
  final_kernel<<<(B_*H_ + 255)/256, 256, 0, stream>>>(rootsel, leaf_h, slot_h, out);
}

// Round 6
// 1881.799 us; speedup vs baseline: 1.0998x; 1.0998x over previous
//
#include <hip/hip_runtime.h>

typedef unsigned short ushort_t;
typedef unsigned long long u64_t;
typedef __attribute__((ext_vector_type(8))) short short8;
typedef __attribute__((ext_vector_type(4))) float floatx4;

#define B_ 256
#define T_ 128
#define E_ 300
#define H_ 512
#define NE_ 127   // T-1 reduce events
#define NT_ 255   // 2T-1 transitions
#define SLH_ 260  // slot_h slots per row (256 live + dump + pad)
#define SLC_ 130  // slot_c slots per row (128 live + dump + pad)
#define ZCODE_ 1023
#define PREVF_ 0x10000

__device__ inline ushort_t f2bf(float f){
  unsigned u = __builtin_bit_cast(unsigned, f);
  unsigned r = u + 0x7FFFu + ((u >> 16) & 1u);
  return (ushort_t)(r >> 16);
}
__device__ inline float bf2f(ushort_t h){
  unsigned u = ((unsigned)h) << 16;
  return __builtin_bit_cast(float, u);
}
__device__ inline float sigm(float x){ return 1.0f / (1.0f + __expf(-x)); }
// exp-based tanh: exact in the tails, ~ulp-level f32 error (<< bf16 noise).
__device__ inline float ftanh(float x){
  float e = __expf(2.0f * x);
  return 1.0f - 2.0f / (e + 1.0f);
}

__device__ inline void store_h_coh64(u64_t* p, u64_t v){
  __hip_atomic_store(p, v, __ATOMIC_RELAXED, __HIP_MEMORY_SCOPE_AGENT);
}

// ---------------------------------------------------------------------------
// x (fp32, rows of 300) -> xb (bf16, rows padded to 320, pad = 0)
// ---------------------------------------------------------------------------
__global__ __launch_bounds__(256) void xcast_kernel(const float* __restrict__ x,
    ushort_t* __restrict__ xb){
  int t = blockIdx.x * 256 + threadIdx.x;
  if (t >= (B_ * T_) * 40) return;
  int row = t / 40, k8 = (t % 40) * 8;
  const float* src = x + (size_t)row * E_;
  short8 v;
  #pragma unroll
  for (int j = 0; j < 8; ++j){
    int k = k8 + j;
    v[j] = (k < E_) ? (short)f2bf(src[k]) : (short)0;
  }
  *(short8*)(xb + (size_t)row * 320 + k8) = v;
}

// ---------------------------------------------------------------------------
// Pack a KxN row-major fp32 weight into MFMA B-fragment order (bf16).
// ---------------------------------------------------------------------------
__global__ __launch_bounds__(256) void pack_w_kernel(const float* __restrict__ W,
    ushort_t* __restrict__ dst, int K, int N, int NS, int total){
  int t = blockIdx.x * 256 + threadIdx.x;
  if (t >= total) return;
  int L = t & 63;
  int s = (t >> 6) % NS;
  int ct = t / (64 * NS);
  int n = ct * 16 + (L & 15);
  int kbase = s * 32 + ((L >> 4) << 3);
  short8 pack;
  #pragma unroll
  for (int j = 0; j < 8; ++j){
    int k = kbase + j;
    pack[j] = (k < K) ? (short)f2bf(W[(size_t)k * N + n]) : (short)0;
  }
  *(short8*)(dst + (size_t)t * 8) = pack;
}

// ---------------------------------------------------------------------------
// Stack machine with SLOT-RECYCLED storage. Codes (low 10 bits):
//   [0,128) leaf | [256,512) node at phys h-slot (c-slot = phys>>1) | 1023 zeros
// PREVF_: child is the previous event's node (c register-carried).
// ---------------------------------------------------------------------------
__global__ void sched_kernel(const int* __restrict__ trans, int* __restrict__ lsel,
    int* __restrict__ rsel, int* __restrict__ wph, int* __restrict__ rootsel){
  __shared__ int stk[32 * 128];    // value code
  __shared__ int stkid[32 * 128];  // node id (T_+e) or leaf idx
  int tid = threadIdx.x;           // 0..31
  int b0 = blockIdx.x * 32;
  int b = b0 + tid;
  for (int i = 0; i < 128; ++i){ stk[tid * 128 + i] = ZCODE_; stkid[tid * 128 + i] = -1; }
  u64_t tog0 = 0, tog1 = 0;
  int sp = 0, bp = T_, e = 0;
  for (int t = 0; t < NT_; ++t){
    int tr = trans[t * B_ + b];
    if (tr == 0){
      int pos = sp; if (pos < 0) pos = 0; if (pos > 127) pos = 127;
      stk[tid * 128 + pos] = bp - 1;
      stkid[tid * 128 + pos] = bp - 1;
      sp += 1; bp -= 1;
    } else {
      int i2 = sp - 2; if (i2 < 0) i2 = 0; if (i2 > 127) i2 = 127;
      int i1 = sp - 1; if (i1 < 0) i1 = 0; if (i1 > 127) i1 = 127;
      if (e < NE_){
        int lc = stk[tid * 128 + i2], rc = stk[tid * 128 + i1];
        int lid = stkid[tid * 128 + i2], rid = stkid[tid * 128 + i1];
        int previd = T_ + e - 1;
        lsel[e * B_ + b] = lc | ((e > 0 && lid == previd) ? PREVF_ : 0);
        rsel[e * B_ + b] = rc | ((e > 0 && rid == previd) ? PREVF_ : 0);
        int pos = i2;
        unsigned ob;
        if (pos < 64){ ob = (unsigned)((tog0 >> pos) & 1); tog0 ^= (1ull << pos); }
        else         { ob = (unsigned)((tog1 >> (pos - 64)) & 1); tog1 ^= (1ull << (pos - 64)); }
        int phys = pos * 2 + (int)(ob ^ 1u);
        wph[e * B_ + b] = phys;
        stk[tid * 128 + pos] = 256 + phys;
        stkid[tid * 128 + pos] = T_ + e;
      }
      e += 1; sp -= 1;
    }
  }
  for (int k = e; k < NE_; ++k){
    lsel[k * B_ + b] = ZCODE_; rsel[k * B_ + b] = ZCODE_;
    wph[k * B_ + b] = 256;     // dump slot — never aliases live slots
  }
  int ip = sp - 1; if (ip < 0) ip = 0; if (ip > 127) ip = 127;
  rootsel[b] = stk[tid * 128 + ip];
}

// ---------------------------------------------------------------------------
// Leaf phase from pre-cast bf16 x (padded K=320). WG = 4 waves x 16 rows =
// 64 rows, 128 cols (8 col-tiles) for both weights. Grid (512, 4).
// ---------------------------------------------------------------------------
__global__ __launch_bounds__(256) void leaf_kernel(const ushort_t* __restrict__ xb,
    const ushort_t* __restrict__ WpP, const ushort_t* __restrict__ WgP,
    const float* __restrict__ b_proj, const float* __restrict__ b_gate,
    ushort_t* __restrict__ leaf_h, ushort_t* __restrict__ leaf_c){
  int wave = threadIdx.x >> 6, lane = threadIdx.x & 63;
  int r0 = blockIdx.x * 64 + wave * 16;
  int cbase = blockIdx.y * 8;
  int arow = r0 + (lane & 15);
  int klane = (lane >> 4) << 3;
  const ushort_t* xrow = xb + (size_t)arow * 320;
  floatx4 accP[8], accG[8];
  #pragma unroll
  for (int i = 0; i < 8; ++i){ accP[i] = (floatx4){0,0,0,0}; accG[i] = (floatx4){0,0,0,0}; }
  #pragma unroll
  for (int s = 0; s < 10; ++s){
    short8 a = *(const short8*)(xrow + s * 32 + klane);
    #pragma unroll
    for (int cc = 0; cc < 8; ++cc){
      short8 bp = *(const short8*)(WpP + (((size_t)(cbase + cc) * 10 + s) * 64 + lane) * 8);
      accP[cc] = __builtin_amdgcn_mfma_f32_16x16x32_bf16(a, bp, accP[cc], 0, 0, 0);
      short8 bg = *(const short8*)(WgP + (((size_t)(cbase + cc) * 10 + s) * 64 + lane) * 8);
      accG[cc] = __builtin_amdgcn_mfma_f32_16x16x32_bf16(a, bg, accG[cc], 0, 0, 0);
    }
  }
  int rbase = r0 + ((lane >> 4) << 2);
  #pragma unroll
  for (int cc = 0; cc < 8; ++cc){
    int col = (cbase + cc) * 16 + (lane & 15);
    float bp = b_proj[col], bg = b_gate[col];
    #pragma unroll
    for (int r = 0; r < 4; ++r){
      int row = rbase + r;
      float cv = accP[cc][r] + bp;
      float hv = sigm(accG[cc][r] + bg) * ftanh(cv);
      size_t o = (size_t)row * H_ + col;
      leaf_c[o] = f2bf(cv);
      leaf_h[o] = f2bf(hv);
    }
  }
}

// ---------------------------------------------------------------------------
// Persistent chain, R13. Protocol identical to R8/R12 (agent-scope flags on
// 32 distinct 128B lines, two-barrier structure, wave0 polls). Three latency
// cuts using only proven constructs:
//  1. Node-A loads: all 32 8B agent loads issued into a register union FIRST
//     (combine later) so the compiler emits ONE vmcnt wait over the whole
//     pipelined burst, instead of a wait per 16B pair (was up to 16 serial
//     ~700cy L3 round trips per wave).
//  2. Producer h stores: pack 32 rows x 16 cols through 1KB LDS, then each
//     lane issues two 8B agent stores (16B contiguous). 8 scattered 2B ops
//     -> 2 wide ops per lane; full 32B segments per row (less L3 partial-
//     line RMW, shorter vmcnt drain, lower WRITE amplification).
//  3. Flag poll: escalating s_sleep backoff (0 -> 2 -> 8) to stop 256 wave0s
//     from hammering the flag lines while producers try to store to them.
// Also: node slot_c reads moved PRE-wait (same-block data written >=1 event
// ago behind a prior vmcnt(0) drain — no cross-block dependency).
// ---------------------------------------------------------------------------
__global__ __launch_bounds__(256, 1) void chain_kernel(
    const ushort_t* __restrict__ WrP, const float* __restrict__ b_reduce,
    const ushort_t* __restrict__ leaf_h, const ushort_t* __restrict__ leaf_c,
    ushort_t* __restrict__ slot_h, float* __restrict__ slot_c,
    const int* __restrict__ lsel, const int* __restrict__ rsel,
    const int* __restrict__ wph, const ushort_t* __restrict__ zbuf,
    unsigned* __restrict__ gflags){
  __shared__ floatx4 part[3][2][5][64];   // [kq-1][rt][g][lane] — conflict-free
  __shared__ ushort_t hpack[32][16];      // wave0 h-store packing (1KB)
  const int bid  = blockIdx.x;
  const int cth  = bid >> 3;
  const int rg   = bid & 7;
  const int kq   = threadIdx.x >> 6;     // wave = K-quarter
  const int lane = threadIdx.x & 63;
  const int m16  = lane & 15;
  const int klane = (lane >> 4) << 3;
  const int colh = cth * 16 + m16;
  const int row0 = rg * 32;
  float bias[5];
  if (kq == 0){
    #pragma unroll
    for (int g = 0; g < 5; ++g) bias[g] = b_reduce[g * H_ + colh];
  }
  const int* ssel = (kq < 2) ? lsel : rsel;    // kq 0,1 = left child half
  const int kcolbase = (kq & 1) * 256;         // col offset within child h
  unsigned* myflag  = gflags + ((unsigned)(rg * 32 + cth) << 5);       // 128B stride
  unsigned* pollptr = gflags + ((unsigned)(rg * 32 + (lane & 31)) << 5);
  float creg[2][4];                            // c written last event (wave 0)
  #pragma unroll
  for (int rt = 0; rt < 2; ++rt)
    #pragma unroll
    for (int r = 0; r < 4; ++r) creg[rt][r] = 0.0f;

  #pragma unroll 1
  for (int e = 0; e < NE_; ++e){
    // ---- child codes ----
    int code[2];
    const ushort_t* leafp[2];
    #pragma unroll
    for (int rt = 0; rt < 2; ++rt){
      int row = row0 + rt * 16 + m16;
      code[rt] = ssel[e * B_ + row] & 0x3FF;
      leafp[rt] = (code[rt] < 128) ? leaf_h + ((size_t)row * T_ + code[rt]) * H_ + kcolbase
                                   : zbuf;
    }

    // ---- W fragments: load + pin in regs BEFORE the wait (L2-hit) ----
    short8 Wreg[5][8];
    #pragma unroll
    for (int g = 0; g < 5; ++g)
      #pragma unroll
      for (int s = 0; s < 8; ++s)
        Wreg[g][s] = *(const short8*)(WrP + (((size_t)(g * 32 + cth) * 32 + kq * 8 + s) * 64 + lane) * 8);
    #pragma unroll
    for (int g = 0; g < 5; ++g)
      asm volatile("" : "+v"(Wreg[g][0]), "+v"(Wreg[g][1]), "+v"(Wreg[g][2]),
                        "+v"(Wreg[g][3]), "+v"(Wreg[g][4]), "+v"(Wreg[g][5]),
                        "+v"(Wreg[g][6]), "+v"(Wreg[g][7]));

    // ---- leaf-child A prefetch (independent of previous event) ----
    union AB { u64_t q[16]; short8 v[8]; };
    AB ab[2];
    #pragma unroll
    for (int rt = 0; rt < 2; ++rt){
      if (code[rt] < 256 || code[rt] >= 512){
        #pragma unroll
        for (int s = 0; s < 8; ++s) ab[rt].v[s] = *(const short8*)(leafp[rt] + s * 32 + klane);
      }
    }

    // ---- wave 0: ALL c operands pre-wait (leaf / PREVF regs / own slot_c) ----
    float cl[2][4], cr[2][4];
    if (kq == 0){
      #pragma unroll
      for (int rt = 0; rt < 2; ++rt){
        int rbase = row0 + rt * 16 + ((lane >> 4) << 2);
        #pragma unroll
        for (int r = 0; r < 4; ++r){
          const int bb = rbase + r;
          const int ls = lsel[e * B_ + bb], rs = rsel[e * B_ + bb];
          int lc = ls & 0x3FF, rc = rs & 0x3FF;
          float lv = 0.0f, rv = 0.0f;
          if (ls & PREVF_) lv = creg[rt][r];
          else if (lc < 128) lv = bf2f(leaf_c[((size_t)bb * T_ + lc) * H_ + colh]);
          else if (lc < 512) lv = slot_c[((size_t)bb * SLC_ + ((lc - 256) >> 1)) * H_ + colh];
          if (rs & PREVF_) rv = creg[rt][r];
          else if (rc < 128) rv = bf2f(leaf_c[((size_t)bb * T_ + rc) * H_ + colh]);
          else if (rc < 512) rv = slot_c[((size_t)bb * SLC_ + ((rc - 256) >> 1)) * H_ + colh];
          cl[rt][r] = lv; cr[rt][r] = rv;
        }
      }
    }

    // ---- wait: wave 0 gathers 32 distinct flag lines; backoff; S1 releases ----
    if (kq == 0 && e > 0){
      const unsigned tgt = (unsigned)e;
      int it = 0;
      for (;;){
        unsigned v = __hip_atomic_load(pollptr, __ATOMIC_RELAXED, __HIP_MEMORY_SCOPE_AGENT);
        if (__all(v >= tgt)) break;
        if (it < 2)       __builtin_amdgcn_s_sleep(0);
        else if (it < 16) __builtin_amdgcn_s_sleep(2);
        else              __builtin_amdgcn_s_sleep(8);
        ++it;
      }
    }
    __syncthreads();   // S1: release; also LDS WAR guard for `part`

    // ---- node-child A loads: batch-issue ALL 8B agent loads, combine via union ----
    #pragma unroll
    for (int rt = 0; rt < 2; ++rt){
      if (code[rt] >= 256 && code[rt] < 512){
        int row = row0 + rt * 16 + m16;
        const ushort_t* p = slot_h + ((size_t)row * SLH_ + (code[rt] - 256)) * H_ + kcolbase + klane;
        #pragma unroll
        for (int s = 0; s < 8; ++s){
          ab[rt].q[2 * s]     = __hip_atomic_load((const u64_t*)(p + s * 32),
                                  __ATOMIC_RELAXED, __HIP_MEMORY_SCOPE_AGENT);
          ab[rt].q[2 * s + 1] = __hip_atomic_load((const u64_t*)(p + s * 32 + 4),
                                  __ATOMIC_RELAXED, __HIP_MEMORY_SCOPE_AGENT);
        }
      }
    }

    // ---- MFMA: B from pinned registers ----
    floatx4 acc[2][5];
    #pragma unroll
    for (int rt = 0; rt < 2; ++rt)
      #pragma unroll
      for (int g = 0; g < 5; ++g) acc[rt][g] = (floatx4){0,0,0,0};
    #pragma unroll
    for (int s = 0; s < 8; ++s){
      #pragma unroll
      for (int g = 0; g < 5; ++g){
        acc[0][g] = __builtin_amdgcn_mfma_f32_16x16x32_bf16(ab[0].v[s], Wreg[g][s], acc[0][g], 0, 0, 0);
        acc[1][g] = __builtin_amdgcn_mfma_f32_16x16x32_bf16(ab[1].v[s], Wreg[g][s], acc[1][g], 0, 0, 0);
      }
    }
    if (kq != 0){
      #pragma unroll
      for (int rt = 0; rt < 2; ++rt)
        #pragma unroll
        for (int g = 0; g < 5; ++g)
          part[kq - 1][rt][g][lane] = acc[rt][g];
    }
    __syncthreads();   // S2: partials visible to wave 0
    if (kq == 0){
      #pragma unroll
      for (int rt = 0; rt < 2; ++rt)
        #pragma unroll
        for (int g = 0; g < 5; ++g){
          floatx4 p0 = part[0][rt][g][lane];
          floatx4 p1 = part[1][rt][g][lane];
          floatx4 p2 = part[2][rt][g][lane];
          #pragma unroll
          for (int r = 0; r < 4; ++r) acc[rt][g][r] += p0[r] + p1[r] + p2[r];
        }
      #pragma unroll
      for (int rt = 0; rt < 2; ++rt){
        int rloc0 = rt * 16 + ((lane >> 4) << 2);
        int rbase = row0 + rloc0;
        #pragma unroll
        for (int r = 0; r < 4; ++r){
          const int bb = rbase + r;
          float cn = sigm(acc[rt][1][r] + bias[1]) * cl[rt][r]
                   + sigm(acc[rt][2][r] + bias[2]) * cr[rt][r]
                   + sigm(acc[rt][0][r] + bias[0]) * ftanh(acc[rt][3][r] + bias[3]);
          float hn = sigm(acc[rt][4][r] + bias[4]) * ftanh(cn);
          creg[rt][r] = cn;
          const int w = wph[e * B_ + bb];
          slot_c[((size_t)bb * SLC_ + (w >> 1)) * H_ + colh] = cn;   // WG-private
          hpack[rloc0 + r][m16] = f2bf(hn);                          // LDS pack
        }
      }
      // packed h store: lane L covers row (L>>1), col-half (L&1): 16B per lane
      {
        int rl = lane >> 1, half = lane & 1;
        int bb2 = row0 + rl;
        int w2 = wph[e * B_ + bb2];
        ushort_t* dst = slot_h + ((size_t)bb2 * SLH_ + w2) * H_ + cth * 16 + half * 8;
        u64_t q0 = *(const u64_t*)&hpack[rl][half * 8];
        u64_t q1 = *(const u64_t*)&hpack[rl][half * 8 + 4];
        store_h_coh64((u64_t*)dst, q0);
        store_h_coh64((u64_t*)(dst + 4), q1);
      }
      asm volatile("s_waitcnt vmcnt(0)" ::: "memory");   // drain h stores
      if (threadIdx.x == 0)
        __hip_atomic_store(myflag, (unsigned)(e + 1),
                           __ATOMIC_RELAXED, __HIP_MEMORY_SCOPE_AGENT);
    }
  }
}

// Final: out[b][j] = h of root (leaf / node slot / zeros). Covers every row.
__global__ __launch_bounds__(256) void final_kernel(const int* __restrict__ rootsel,
    const ushort_t* __restrict__ leaf_h, const ushort_t* __restrict__ slot_h,
    float* __restrict__ out){
  int i = blockIdx.x * 256 + threadIdx.x;
  if (i >= B_ * H_) return;
  int b = i >> 9, j = i & (H_ - 1);
  int code = rootsel[b] & 0x3FF;
  float v = 0.0f;
  if (code < 128)      v = bf2f(leaf_h[((size_t)b * T_ + code) * H_ + j]);
  else if (code < 512) v = bf2f(slot_h[((size_t)b * SLH_ + (code - 256)) * H_ + j]);
  out[i] = v;
}

extern "C" void kernel_launch(void* const* d_in, const int* in_sizes, int n_in,
                              void* d_out, int out_size, void* d_ws, size_t ws_size,
                              hipStream_t stream){
  const float* x        = (const float*)d_in[0];
  const float* W_proj   = (const float*)d_in[1];
  const float* b_proj   = (const float*)d_in[2];
  const float* W_gate   = (const float*)d_in[3];
  const float* b_gate   = (const float*)d_in[4];
  const float* W_reduce = (const float*)d_in[5];
  const float* b_reduce = (const float*)d_in[6];
  const int*   trans    = (const int*)d_in[7];
  float* out = (float*)d_out;

  char* ws = (char*)d_ws;
  size_t o = 0;
  ushort_t* WpP    = (ushort_t*)(ws + o); o += (size_t)32*10*64*8*2;    // 0.33 MB
  ushort_t* WgP    = (ushort_t*)(ws + o); o += (size_t)32*10*64*8*2;
  ushort_t* WrP    = (ushort_t*)(ws + o); o += (size_t)160*32*64*8*2;   // 5.24 MB
  ushort_t* leaf_h = (ushort_t*)(ws + o); o += (size_t)B_*T_*H_*2;      // 33.5 MB
  ushort_t* leaf_c = (ushort_t*)(ws + o); o += (size_t)B_*T_*H_*2;      // 33.5 MB
  ushort_t* slot_h = (ushort_t*)(ws + o); o += (size_t)B_*SLH_*H_*2;    // 68.2 MB
  float*    slot_c = (float*)(ws + o);    o += (size_t)B_*SLC_*H_*4;    // 68.2 MB
  int* lsel    = (int*)(ws + o); o += (size_t)NE_*B_*4;
  int* rsel    = (int*)(ws + o); o += (size_t)NE_*B_*4;
  int* wph     = (int*)(ws + o); o += (size_t)NE_*B_*4;
  int* rootsel = (int*)(ws + o); o += (size_t)B_*4;
  unsigned* gflags = (unsigned*)(ws + o); o += (size_t)8 * 32 * 128;  // 1 line per (rg,cth)
  ushort_t* zbuf = (ushort_t*)(ws + o); o += 2048;
  // xb (bf16 x, padded to K=320, 21 MB) overlays slot_c: xb is only read
  // before chain_kernel; slot_c is only accessed during/after it.
  ushort_t* xb = (ushort_t*)slot_c;
  (void)ws_size; (void)in_sizes; (void)n_in; (void)out_size;

  hipMemsetAsync(gflags, 0, (size_t)8 * 32 * 128, stream);
  hipMemsetAsync(zbuf, 0, 2048, stream);
  xcast_kernel<<<((B_*T_)*40 + 255)/256, 256, 0, stream>>>(x, xb);
  pack_w_kernel<<<(32*10*64 + 255)/256, 256, 0, stream>>>(W_proj, WpP, 300, 512, 10, 32*10*64);
  pack_w_kernel<<<(32*10*64 + 255)/256, 256, 0, stream>>>(W_gate, WgP, 300, 512, 10, 32*10*64);
  pack_w_kernel<<<(160*32*64 + 255)/256, 256, 0, stream>>>(W_reduce, WrP, 1024, 2560, 32, 160*32*64);
  sched_kernel<<<8, 32, 0, stream>>>(trans, lsel, rsel, wph, rootsel);
  leaf_kernel<<<dim3(512, 4), 256, 0, stream>>>(xb, WpP, WgP, b_proj, b_gate, leaf_h, leaf_c);
  chain_kernel<<<256, 256, 0, stream>>>(WrP, b_reduce, leaf_h, leaf_c, slot_h, slot_c,
                                        lsel, rsel, wph, zbuf, gflags);
  final_kernel<<<(B_*H_ + 255)/256, 256, 0, stream>>>(rootsel, leaf_h, slot_h, out);
}

// Round 7
// 1172.281 us; speedup vs baseline: 1.7655x; 1.6052x over previous
//
#include <hip/hip_runtime.h>

typedef unsigned short ushort_t;
typedef unsigned long long u64_t;
typedef __attribute__((ext_vector_type(8))) short short8;
typedef __attribute__((ext_vector_type(4))) float floatx4;

#define B_ 256
#define T_ 128
#define E_ 300
#define H_ 512
#define NE_ 127   // T-1 reduce events
#define NT_ 255   // 2T-1 transitions
#define SLH_ 260  // slot_h slots per row (256 live + dump + pad)
#define SLC_ 130  // slot_c slots per row (128 live + dump + pad)
#define ZCODE_ 1023
#define PREVF_ 0x10000

__device__ inline ushort_t f2bf(float f){
  unsigned u = __builtin_bit_cast(unsigned, f);
  unsigned r = u + 0x7FFFu + ((u >> 16) & 1u);
  return (ushort_t)(r >> 16);
}
__device__ inline float bf2f(ushort_t h){
  unsigned u = ((unsigned)h) << 16;
  return __builtin_bit_cast(float, u);
}
__device__ inline float sigm(float x){ return 1.0f / (1.0f + __expf(-x)); }
// exp-based tanh: exact in the tails, ~ulp-level f32 error (<< bf16 noise).
__device__ inline float ftanh(float x){
  float e = __expf(2.0f * x);
  return 1.0f - 2.0f / (e + 1.0f);
}

__device__ inline void store_h_coh64(u64_t* p, u64_t v){
  __hip_atomic_store(p, v, __ATOMIC_RELAXED, __HIP_MEMORY_SCOPE_AGENT);
}

// ---------------------------------------------------------------------------
// x (fp32, rows of 300) -> xb (bf16, rows padded to 320, pad = 0)
// ---------------------------------------------------------------------------
__global__ __launch_bounds__(256) void xcast_kernel(const float* __restrict__ x,
    ushort_t* __restrict__ xb){
  int t = blockIdx.x * 256 + threadIdx.x;
  if (t >= (B_ * T_) * 40) return;
  int row = t / 40, k8 = (t % 40) * 8;
  const float* src = x + (size_t)row * E_;
  short8 v;
  #pragma unroll
  for (int j = 0; j < 8; ++j){
    int k = k8 + j;
    v[j] = (k < E_) ? (short)f2bf(src[k]) : (short)0;
  }
  *(short8*)(xb + (size_t)row * 320 + k8) = v;
}

// ---------------------------------------------------------------------------
// Pack a KxN row-major fp32 weight into MFMA B-fragment order (bf16).
// ---------------------------------------------------------------------------
__global__ __launch_bounds__(256) void pack_w_kernel(const float* __restrict__ W,
    ushort_t* __restrict__ dst, int K, int N, int NS, int total){
  int t = blockIdx.x * 256 + threadIdx.x;
  if (t >= total) return;
  int L = t & 63;
  int s = (t >> 6) % NS;
  int ct = t / (64 * NS);
  int n = ct * 16 + (L & 15);
  int kbase = s * 32 + ((L >> 4) << 3);
  short8 pack;
  #pragma unroll
  for (int j = 0; j < 8; ++j){
    int k = kbase + j;
    pack[j] = (k < K) ? (short)f2bf(W[(size_t)k * N + n]) : (short)0;
  }
  *(short8*)(dst + (size_t)t * 8) = pack;
}

// ---------------------------------------------------------------------------
// Stack machine with SLOT-RECYCLED storage. Codes (low 10 bits):
//   [0,128) leaf | [256,512) node at phys h-slot (c-slot = phys>>1) | 1023 zeros
// PREVF_: child is the previous event's node (c register-carried).
// ---------------------------------------------------------------------------
__global__ void sched_kernel(const int* __restrict__ trans, int* __restrict__ lsel,
    int* __restrict__ rsel, int* __restrict__ wph, int* __restrict__ rootsel){
  __shared__ int stk[32 * 128];    // value code
  __shared__ int stkid[32 * 128];  // node id (T_+e) or leaf idx
  int tid = threadIdx.x;           // 0..31
  int b0 = blockIdx.x * 32;
  int b = b0 + tid;
  for (int i = 0; i < 128; ++i){ stk[tid * 128 + i] = ZCODE_; stkid[tid * 128 + i] = -1; }
  u64_t tog0 = 0, tog1 = 0;
  int sp = 0, bp = T_, e = 0;
  for (int t = 0; t < NT_; ++t){
    int tr = trans[t * B_ + b];
    if (tr == 0){
      int pos = sp; if (pos < 0) pos = 0; if (pos > 127) pos = 127;
      stk[tid * 128 + pos] = bp - 1;
      stkid[tid * 128 + pos] = bp - 1;
      sp += 1; bp -= 1;
    } else {
      int i2 = sp - 2; if (i2 < 0) i2 = 0; if (i2 > 127) i2 = 127;
      int i1 = sp - 1; if (i1 < 0) i1 = 0; if (i1 > 127) i1 = 127;
      if (e < NE_){
        int lc = stk[tid * 128 + i2], rc = stk[tid * 128 + i1];
        int lid = stkid[tid * 128 + i2], rid = stkid[tid * 128 + i1];
        int previd = T_ + e - 1;
        lsel[e * B_ + b] = lc | ((e > 0 && lid == previd) ? PREVF_ : 0);
        rsel[e * B_ + b] = rc | ((e > 0 && rid == previd) ? PREVF_ : 0);
        int pos = i2;
        unsigned ob;
        if (pos < 64){ ob = (unsigned)((tog0 >> pos) & 1); tog0 ^= (1ull << pos); }
        else         { ob = (unsigned)((tog1 >> (pos - 64)) & 1); tog1 ^= (1ull << (pos - 64)); }
        int phys = pos * 2 + (int)(ob ^ 1u);
        wph[e * B_ + b] = phys;
        stk[tid * 128 + pos] = 256 + phys;
        stkid[tid * 128 + pos] = T_ + e;
      }
      e += 1; sp -= 1;
    }
  }
  for (int k = e; k < NE_; ++k){
    lsel[k * B_ + b] = ZCODE_; rsel[k * B_ + b] = ZCODE_;
    wph[k * B_ + b] = 256;     // dump slot — never aliases live slots
  }
  int ip = sp - 1; if (ip < 0) ip = 0; if (ip > 127) ip = 127;
  rootsel[b] = stk[tid * 128 + ip];
}

// ---------------------------------------------------------------------------
// Leaf phase from pre-cast bf16 x (padded K=320). WG = 4 waves x 16 rows =
// 64 rows, 128 cols (8 col-tiles) for both weights. Grid (512, 4).
// ---------------------------------------------------------------------------
__global__ __launch_bounds__(256) void leaf_kernel(const ushort_t* __restrict__ xb,
    const ushort_t* __restrict__ WpP, const ushort_t* __restrict__ WgP,
    const float* __restrict__ b_proj, const float* __restrict__ b_gate,
    ushort_t* __restrict__ leaf_h, ushort_t* __restrict__ leaf_c){
  int wave = threadIdx.x >> 6, lane = threadIdx.x & 63;
  int r0 = blockIdx.x * 64 + wave * 16;
  int cbase = blockIdx.y * 8;
  int arow = r0 + (lane & 15);
  int klane = (lane >> 4) << 3;
  const ushort_t* xrow = xb + (size_t)arow * 320;
  floatx4 accP[8], accG[8];
  #pragma unroll
  for (int i = 0; i < 8; ++i){ accP[i] = (floatx4){0,0,0,0}; accG[i] = (floatx4){0,0,0,0}; }
  #pragma unroll
  for (int s = 0; s < 10; ++s){
    short8 a = *(const short8*)(xrow + s * 32 + klane);
    #pragma unroll
    for (int cc = 0; cc < 8; ++cc){
      short8 bp = *(const short8*)(WpP + (((size_t)(cbase + cc) * 10 + s) * 64 + lane) * 8);
      accP[cc] = __builtin_amdgcn_mfma_f32_16x16x32_bf16(a, bp, accP[cc], 0, 0, 0);
      short8 bg = *(const short8*)(WgP + (((size_t)(cbase + cc) * 10 + s) * 64 + lane) * 8);
      accG[cc] = __builtin_amdgcn_mfma_f32_16x16x32_bf16(a, bg, accG[cc], 0, 0, 0);
    }
  }
  int rbase = r0 + ((lane >> 4) << 2);
  #pragma unroll
  for (int cc = 0; cc < 8; ++cc){
    int col = (cbase + cc) * 16 + (lane & 15);
    float bp = b_proj[col], bg = b_gate[col];
    #pragma unroll
    for (int r = 0; r < 4; ++r){
      int row = rbase + r;
      float cv = accP[cc][r] + bp;
      float hv = sigm(accG[cc][r] + bg) * ftanh(cv);
      size_t o = (size_t)row * H_ + col;
      leaf_c[o] = f2bf(cv);
      leaf_h[o] = f2bf(hv);
    }
  }
}

// ---------------------------------------------------------------------------
// Persistent chain, R14. Protocol = R8/R13 (agent-scope flags on distinct
// 128B lines, per-event flag after drain, poll-with-backoff). Structural
// changes (proven constructs only):
//  1. ROLE SWAP: waves 0,1 take the RIGHT child (rsel, W K-quarters 2,3),
//     waves 2,3 the LEFT (lsel, quarters 0,1). Per-rt, leaf/zero children
//     run their MFMAs BEFORE the flag wait (overlapping it); only node rts
//     poll (16 flag lines = their 256-col producers) and load post-wait.
//     In the dominant pattern (left=prev node, right=fresh leaf) this moves
//     half the MFMAs + all leaf loads off the serial path.
//  2. DISTRIBUTED reduce/epilogue: ALL waves write partials to LDS
//     part[4][2][5][64]; each wave reduces + epilogues its own 8 rows
//     (2 cells/lane, was 8 on wave0), stores its own h slice (32 lanes x
//     8B contiguous), drains its own stores; one barrier; thread0 flags.
//     Wave0's ~2500cy serial section shrinks ~4x; drains parallelize.
//  3. Per-wave c-operand prefetch pre-wait; creg carried by owning wave.
// ---------------------------------------------------------------------------
__global__ __launch_bounds__(256, 1) void chain_kernel(
    const ushort_t* __restrict__ WrP, const float* __restrict__ b_reduce,
    const ushort_t* __restrict__ leaf_h, const ushort_t* __restrict__ leaf_c,
    ushort_t* __restrict__ slot_h, float* __restrict__ slot_c,
    const int* __restrict__ lsel, const int* __restrict__ rsel,
    const int* __restrict__ wph, const ushort_t* __restrict__ zbuf,
    unsigned* __restrict__ gflags){
  __shared__ floatx4 part[4][2][5][64];                       // 40 KB
  __shared__ ushort_t hp[4][8][16] __attribute__((aligned(8))); // 1 KB
  const int bid  = blockIdx.x;
  const int cth  = bid >> 3;
  const int rg   = bid & 7;
  const int kq   = threadIdx.x >> 6;     // wave
  const int lane = threadIdx.x & 63;
  const int m16  = lane & 15;
  const int klane = (lane >> 4) << 3;
  const int colh = cth * 16 + m16;
  const int row0 = rg * 32;
  // role: waves 0,1 -> RIGHT child (rsel), W K-quarters 2,3 (K [512,1024))
  //       waves 2,3 -> LEFT  child (lsel), W K-quarters 0,1 (K [0,512))
  const int* ssel = (kq < 2) ? rsel : lsel;
  const int qK    = (kq < 2) ? (2 + kq) : (kq - 2);
  const int kcolbase = (kq & 1) * 256;   // col offset within child h
  float bias[5];
  #pragma unroll
  for (int g = 0; g < 5; ++g) bias[g] = b_reduce[g * H_ + colh];
  unsigned* myflag  = gflags + ((unsigned)(rg * 32 + cth) << 5);            // 128B stride
  unsigned* pollptr = gflags + ((unsigned)(rg * 32 + (kq & 1) * 16 + m16) << 5);
  const int err_ = lane >> 4;            // epilogue row sub-slot (0..3)
  float creg[2] = {0.0f, 0.0f};          // prev-event c for owned rows

  #pragma unroll 1
  for (int e = 0; e < NE_; ++e){
    // ---- child codes per rt ----
    int code[2];
    const ushort_t* leafp[2];
    #pragma unroll
    for (int rt = 0; rt < 2; ++rt){
      int row = row0 + rt * 16 + m16;
      code[rt] = ssel[e * B_ + row] & 0x3FF;
      leafp[rt] = (code[rt] < 128) ? leaf_h + ((size_t)row * T_ + code[rt]) * H_ + kcolbase
                                   : zbuf;
    }
    const bool isnode0 = (code[0] >= 256 && code[0] < 512);
    const bool isnode1 = (code[1] >= 256 && code[1] < 512);

    // ---- W fragments: load + pin (L2-hit, invariant data) ----
    short8 Wreg[5][8];
    #pragma unroll
    for (int g = 0; g < 5; ++g)
      #pragma unroll
      for (int s = 0; s < 8; ++s)
        Wreg[g][s] = *(const short8*)(WrP + (((size_t)(g * 32 + cth) * 32 + qK * 8 + s) * 64 + lane) * 8);
    #pragma unroll
    for (int g = 0; g < 5; ++g)
      asm volatile("" : "+v"(Wreg[g][0]), "+v"(Wreg[g][1]), "+v"(Wreg[g][2]),
                        "+v"(Wreg[g][3]), "+v"(Wreg[g][4]), "+v"(Wreg[g][5]),
                        "+v"(Wreg[g][6]), "+v"(Wreg[g][7]));

    // ---- leaf/zero child prefetch (no wait needed) ----
    union AB { u64_t q[16]; short8 v[8]; };
    AB ab[2];
    #pragma unroll
    for (int rt = 0; rt < 2; ++rt){
      if (!(rt == 0 ? isnode0 : isnode1)){
        #pragma unroll
        for (int s = 0; s < 8; ++s) ab[rt].v[s] = *(const short8*)(leafp[rt] + s * 32 + klane);
      }
    }

    // ---- per-wave epilogue operand prefetch (owned rows: kq*8 .. kq*8+8) ----
    float cl[2], cr[2];
    int wv[2];
    #pragma unroll
    for (int rix = 0; rix < 2; ++rix){
      const int R  = kq * 8 + err_ * 2 + rix;
      const int bb = row0 + R;
      const int ls = lsel[e * B_ + bb], rs = rsel[e * B_ + bb];
      wv[rix] = wph[e * B_ + bb];
      int lc = ls & 0x3FF, rc = rs & 0x3FF;
      float lv = 0.0f, rv = 0.0f;
      if (ls & PREVF_) lv = creg[rix];
      else if (lc < 128) lv = bf2f(leaf_c[((size_t)bb * T_ + lc) * H_ + colh]);
      else if (lc < 512) lv = slot_c[((size_t)bb * SLC_ + ((lc - 256) >> 1)) * H_ + colh];
      if (rs & PREVF_) rv = creg[rix];
      else if (rc < 128) rv = bf2f(leaf_c[((size_t)bb * T_ + rc) * H_ + colh]);
      else if (rc < 512) rv = slot_c[((size_t)bb * SLC_ + ((rc - 256) >> 1)) * H_ + colh];
      cl[rix] = lv; cr[rix] = rv;
    }

    // ---- pre-wait MFMA for leaf/zero rts; partials to LDS early ----
    floatx4 acc[2][5];
    #pragma unroll
    for (int rt = 0; rt < 2; ++rt)
      #pragma unroll
      for (int g = 0; g < 5; ++g) acc[rt][g] = (floatx4){0,0,0,0};
    #pragma unroll
    for (int rt = 0; rt < 2; ++rt){
      if (!(rt == 0 ? isnode0 : isnode1)){
        #pragma unroll
        for (int s = 0; s < 8; ++s)
          #pragma unroll
          for (int g = 0; g < 5; ++g)
            acc[rt][g] = __builtin_amdgcn_mfma_f32_16x16x32_bf16(ab[rt].v[s], Wreg[g][s], acc[rt][g], 0, 0, 0);
        #pragma unroll
        for (int g = 0; g < 5; ++g) part[kq][rt][g][lane] = acc[rt][g];
      }
    }

    // ---- wait (only waves with a node child; 16 producer lines) ----
    if (isnode0 || isnode1){
      const unsigned tgt = (unsigned)e;
      int it = 0;
      for (;;){
        unsigned v = __hip_atomic_load(pollptr, __ATOMIC_RELAXED, __HIP_MEMORY_SCOPE_AGENT);
        if (__all(v >= tgt)) break;
        if (it < 2)       __builtin_amdgcn_s_sleep(0);
        else if (it < 16) __builtin_amdgcn_s_sleep(2);
        else              __builtin_amdgcn_s_sleep(8);
        ++it;
      }
    }

    // ---- node-child loads (batched agent 8B) + MFMA + partials ----
    #pragma unroll
    for (int rt = 0; rt < 2; ++rt){
      if (rt == 0 ? isnode0 : isnode1){
        int row = row0 + rt * 16 + m16;
        const ushort_t* p = slot_h + ((size_t)row * SLH_ + (code[rt] - 256)) * H_ + kcolbase + klane;
        #pragma unroll
        for (int s = 0; s < 8; ++s){
          ab[rt].q[2 * s]     = __hip_atomic_load((const u64_t*)(p + s * 32),
                                  __ATOMIC_RELAXED, __HIP_MEMORY_SCOPE_AGENT);
          ab[rt].q[2 * s + 1] = __hip_atomic_load((const u64_t*)(p + s * 32 + 4),
                                  __ATOMIC_RELAXED, __HIP_MEMORY_SCOPE_AGENT);
        }
        #pragma unroll
        for (int s = 0; s < 8; ++s)
          #pragma unroll
          for (int g = 0; g < 5; ++g)
            acc[rt][g] = __builtin_amdgcn_mfma_f32_16x16x32_bf16(ab[rt].v[s], Wreg[g][s], acc[rt][g], 0, 0, 0);
        #pragma unroll
        for (int g = 0; g < 5; ++g) part[kq][rt][g][lane] = acc[rt][g];
      }
    }
    __syncthreads();   // S2: all partials visible

    // ---- distributed reduce + epilogue: 2 cells/lane on owned rows ----
    #pragma unroll
    for (int rix = 0; rix < 2; ++rix){
      const int R    = kq * 8 + err_ * 2 + rix;
      const int bb   = row0 + R;
      const int rt2  = R >> 4;
      const int lane2 = (((R >> 2) & 3) << 4) + m16;
      const int rsub = R & 3;
      float o[5];
      #pragma unroll
      for (int g = 0; g < 5; ++g)
        o[g] = part[0][rt2][g][lane2][rsub] + part[1][rt2][g][lane2][rsub]
             + part[2][rt2][g][lane2][rsub] + part[3][rt2][g][lane2][rsub] + bias[g];
      float cn = sigm(o[1]) * cl[rix] + sigm(o[2]) * cr[rix] + sigm(o[0]) * ftanh(o[3]);
      float hn = sigm(o[4]) * ftanh(cn);
      creg[rix] = cn;
      slot_c[((size_t)bb * SLC_ + (wv[rix] >> 1)) * H_ + colh] = cn;   // WG-private
      hp[kq][err_ * 2 + rix][m16] = f2bf(hn);
    }
    // ---- per-wave packed h store: lanes 0-31, 8B contiguous each ----
    if (lane < 32){
      int rl = lane >> 2, qw = lane & 3;
      int bb2 = row0 + kq * 8 + rl;
      int w2 = wph[e * B_ + bb2];
      ushort_t* dst = slot_h + ((size_t)bb2 * SLH_ + w2) * H_ + cth * 16 + qw * 4;
      u64_t qv = *(const u64_t*)&hp[kq][rl][qw * 4];
      store_h_coh64((u64_t*)dst, qv);
    }
    asm volatile("s_waitcnt vmcnt(0)" ::: "memory");   // drain own stores
    __syncthreads();   // S3: all waves drained; part/hp reads done (WAR guard)
    if (threadIdx.x == 0)
      __hip_atomic_store(myflag, (unsigned)(e + 1),
                         __ATOMIC_RELAXED, __HIP_MEMORY_SCOPE_AGENT);
  }
}

// Final: out[b][j] = h of root (leaf / node slot / zeros). Covers every row.
__global__ __launch_bounds__(256) void final_kernel(const int* __restrict__ rootsel,
    const ushort_t* __restrict__ leaf_h, const ushort_t* __restrict__ slot_h,
    float* __restrict__ out){
  int i = blockIdx.x * 256 + threadIdx.x;
  if (i >= B_ * H_) return;
  int b = i >> 9, j = i & (H_ - 1);
  int code = rootsel[b] & 0x3FF;
  float v = 0.0f;
  if (code < 128)      v = bf2f(leaf_h[((size_t)b * T_ + code) * H_ + j]);
  else if (code < 512) v = bf2f(slot_h[((size_t)b * SLH_ + (code - 256)) * H_ + j]);
  out[i] = v;
}

extern "C" void kernel_launch(void* const* d_in, const int* in_sizes, int n_in,
                              void* d_out, int out_size, void* d_ws, size_t ws_size,
                              hipStream_t stream){
  const float* x        = (const float*)d_in[0];
  const float* W_proj   = (const float*)d_in[1];
  const float* b_proj   = (const float*)d_in[2];
  const float* W_gate   = (const float*)d_in[3];
  const float* b_gate   = (const float*)d_in[4];
  const float* W_reduce = (const float*)d_in[5];
  const float* b_reduce = (const float*)d_in[6];
  const int*   trans    = (const int*)d_in[7];
  float* out = (float*)d_out;

  char* ws = (char*)d_ws;
  size_t o = 0;
  ushort_t* WpP    = (ushort_t*)(ws + o); o += (size_t)32*10*64*8*2;    // 0.33 MB
  ushort_t* WgP    = (ushort_t*)(ws + o); o += (size_t)32*10*64*8*2;
  ushort_t* WrP    = (ushort_t*)(ws + o); o += (size_t)160*32*64*8*2;   // 5.24 MB
  ushort_t* leaf_h = (ushort_t*)(ws + o); o += (size_t)B_*T_*H_*2;      // 33.5 MB
  ushort_t* leaf_c = (ushort_t*)(ws + o); o += (size_t)B_*T_*H_*2;      // 33.5 MB
  ushort_t* slot_h = (ushort_t*)(ws + o); o += (size_t)B_*SLH_*H_*2;    // 68.2 MB
  float*    slot_c = (float*)(ws + o);    o += (size_t)B_*SLC_*H_*4;    // 68.2 MB
  int* lsel    = (int*)(ws + o); o += (size_t)NE_*B_*4;
  int* rsel    = (int*)(ws + o); o += (size_t)NE_*B_*4;
  int* wph     = (int*)(ws + o); o += (size_t)NE_*B_*4;
  int* rootsel = (int*)(ws + o); o += (size_t)B_*4;
  unsigned* gflags = (unsigned*)(ws + o); o += (size_t)8 * 32 * 128;  // 1 line per (rg,cth)
  ushort_t* zbuf = (ushort_t*)(ws + o); o += 2048;
  // xb (bf16 x, padded to K=320, 21 MB) overlays slot_c: xb is only read
  // before chain_kernel; slot_c is only accessed during/after it.
  ushort_t* xb = (ushort_t*)slot_c;
  (void)ws_size; (void)in_sizes; (void)n_in; (void)out_size;

  hipMemsetAsync(gflags, 0, (size_t)8 * 32 * 128, stream);
  hipMemsetAsync(zbuf, 0, 2048, stream);
  xcast_kernel<<<((B_*T_)*40 + 255)/256, 256, 0, stream>>>(x, xb);
  pack_w_kernel<<<(32*10*64 + 255)/256, 256, 0, stream>>>(W_proj, WpP, 300, 512, 10, 32*10*64);
  pack_w_kernel<<<(32*10*64 + 255)/256, 256, 0, stream>>>(W_gate, WgP, 300, 512, 10, 32*10*64);
  pack_w_kernel<<<(160*32*64 + 255)/256, 256, 0, stream>>>(W_reduce, WrP, 1024, 2560, 32, 160*32*64);
  sched_kernel<<<8, 32, 0, stream>>>(trans, lsel, rsel, wph, rootsel);
  leaf_kernel<<<dim3(512, 4), 256, 0, stream>>>(xb, WpP, WgP, b_proj, b_gate, leaf_h, leaf_c);
  chain_kernel<<<256, 256, 0, stream>>>(WrP, b_reduce, leaf_h, leaf_c, slot_h, slot_c,
                                        lsel, rsel, wph, zbuf, gflags);
  final_kernel<<<(B_*H_ + 255)/256, 256, 0, stream>>>(rootsel, leaf_h, slot_h, out);
}

// Round 8
// 1167.995 us; speedup vs baseline: 1.7720x; 1.0037x over previous
//
#include <hip/hip_runtime.h>

typedef unsigned short ushort_t;
typedef unsigned long long u64_t;
typedef __attribute__((ext_vector_type(8))) short short8;
typedef __attribute__((ext_vector_type(4))) float floatx4;

#define B_ 256
#define T_ 128
#define E_ 300
#define H_ 512
#define NE_ 127   // T-1 reduce events
#define NT_ 255   // 2T-1 transitions
#define SLH_ 260  // slot_h slots per row (256 live + dump + pad)
#define SLC_ 130  // slot_c slots per row (128 live + dump + pad)
#define ZCODE_ 1023
#define PREVF_ 0x10000

__device__ inline ushort_t f2bf(float f){
  unsigned u = __builtin_bit_cast(unsigned, f);
  unsigned r = u + 0x7FFFu + ((u >> 16) & 1u);
  return (ushort_t)(r >> 16);
}
__device__ inline float bf2f(ushort_t h){
  unsigned u = ((unsigned)h) << 16;
  return __builtin_bit_cast(float, u);
}
__device__ inline float sigm(float x){ return 1.0f / (1.0f + __expf(-x)); }
// exp-based tanh: exact in the tails, ~ulp-level f32 error (<< bf16 noise).
__device__ inline float ftanh(float x){
  float e = __expf(2.0f * x);
  return 1.0f - 2.0f / (e + 1.0f);
}

__device__ inline void store_h_coh64(u64_t* p, u64_t v){
  __hip_atomic_store(p, v, __ATOMIC_RELAXED, __HIP_MEMORY_SCOPE_AGENT);
}

// ---------------------------------------------------------------------------
// x (fp32, rows of 300) -> xb (bf16, rows padded to 320, pad = 0)
// ---------------------------------------------------------------------------
__global__ __launch_bounds__(256) void xcast_kernel(const float* __restrict__ x,
    ushort_t* __restrict__ xb){
  int t = blockIdx.x * 256 + threadIdx.x;
  if (t >= (B_ * T_) * 40) return;
  int row = t / 40, k8 = (t % 40) * 8;
  const float* src = x + (size_t)row * E_;
  short8 v;
  #pragma unroll
  for (int j = 0; j < 8; ++j){
    int k = k8 + j;
    v[j] = (k < E_) ? (short)f2bf(src[k]) : (short)0;
  }
  *(short8*)(xb + (size_t)row * 320 + k8) = v;
}

// ---------------------------------------------------------------------------
// Pack a KxN row-major fp32 weight into MFMA B-fragment order (bf16).
// ---------------------------------------------------------------------------
__global__ __launch_bounds__(256) void pack_w_kernel(const float* __restrict__ W,
    ushort_t* __restrict__ dst, int K, int N, int NS, int total){
  int t = blockIdx.x * 256 + threadIdx.x;
  if (t >= total) return;
  int L = t & 63;
  int s = (t >> 6) % NS;
  int ct = t / (64 * NS);
  int n = ct * 16 + (L & 15);
  int kbase = s * 32 + ((L >> 4) << 3);
  short8 pack;
  #pragma unroll
  for (int j = 0; j < 8; ++j){
    int k = kbase + j;
    pack[j] = (k < K) ? (short)f2bf(W[(size_t)k * N + n]) : (short)0;
  }
  *(short8*)(dst + (size_t)t * 8) = pack;
}

// ---------------------------------------------------------------------------
// Stack machine with SLOT-RECYCLED storage. Codes (low 10 bits):
//   [0,128) leaf | [256,512) node at phys h-slot (c-slot = phys>>1) | 1023 zeros
// PREVF_: child is the previous event's node (c register-carried).
// ---------------------------------------------------------------------------
__global__ void sched_kernel(const int* __restrict__ trans, int* __restrict__ lsel,
    int* __restrict__ rsel, int* __restrict__ wph, int* __restrict__ rootsel){
  __shared__ int stk[32 * 128];    // value code
  __shared__ int stkid[32 * 128];  // node id (T_+e) or leaf idx
  int tid = threadIdx.x;           // 0..31
  int b0 = blockIdx.x * 32;
  int b = b0 + tid;
  for (int i = 0; i < 128; ++i){ stk[tid * 128 + i] = ZCODE_; stkid[tid * 128 + i] = -1; }
  u64_t tog0 = 0, tog1 = 0;
  int sp = 0, bp = T_, e = 0;
  for (int t = 0; t < NT_; ++t){
    int tr = trans[t * B_ + b];
    if (tr == 0){
      int pos = sp; if (pos < 0) pos = 0; if (pos > 127) pos = 127;
      stk[tid * 128 + pos] = bp - 1;
      stkid[tid * 128 + pos] = bp - 1;
      sp += 1; bp -= 1;
    } else {
      int i2 = sp - 2; if (i2 < 0) i2 = 0; if (i2 > 127) i2 = 127;
      int i1 = sp - 1; if (i1 < 0) i1 = 0; if (i1 > 127) i1 = 127;
      if (e < NE_){
        int lc = stk[tid * 128 + i2], rc = stk[tid * 128 + i1];
        int lid = stkid[tid * 128 + i2], rid = stkid[tid * 128 + i1];
        int previd = T_ + e - 1;
        lsel[e * B_ + b] = lc | ((e > 0 && lid == previd) ? PREVF_ : 0);
        rsel[e * B_ + b] = rc | ((e > 0 && rid == previd) ? PREVF_ : 0);
        int pos = i2;
        unsigned ob;
        if (pos < 64){ ob = (unsigned)((tog0 >> pos) & 1); tog0 ^= (1ull << pos); }
        else         { ob = (unsigned)((tog1 >> (pos - 64)) & 1); tog1 ^= (1ull << (pos - 64)); }
        int phys = pos * 2 + (int)(ob ^ 1u);
        wph[e * B_ + b] = phys;
        stk[tid * 128 + pos] = 256 + phys;
        stkid[tid * 128 + pos] = T_ + e;
      }
      e += 1; sp -= 1;
    }
  }
  for (int k = e; k < NE_; ++k){
    lsel[k * B_ + b] = ZCODE_; rsel[k * B_ + b] = ZCODE_;
    wph[k * B_ + b] = 256;     // dump slot — never aliases live slots
  }
  int ip = sp - 1; if (ip < 0) ip = 0; if (ip > 127) ip = 127;
  rootsel[b] = stk[tid * 128 + ip];
}

// ---------------------------------------------------------------------------
// Leaf phase from pre-cast bf16 x (padded K=320). WG = 4 waves x 16 rows =
// 64 rows, 128 cols (8 col-tiles) for both weights. Grid (512, 4).
// ---------------------------------------------------------------------------
__global__ __launch_bounds__(256) void leaf_kernel(const ushort_t* __restrict__ xb,
    const ushort_t* __restrict__ WpP, const ushort_t* __restrict__ WgP,
    const float* __restrict__ b_proj, const float* __restrict__ b_gate,
    ushort_t* __restrict__ leaf_h, ushort_t* __restrict__ leaf_c){
  int wave = threadIdx.x >> 6, lane = threadIdx.x & 63;
  int r0 = blockIdx.x * 64 + wave * 16;
  int cbase = blockIdx.y * 8;
  int arow = r0 + (lane & 15);
  int klane = (lane >> 4) << 3;
  const ushort_t* xrow = xb + (size_t)arow * 320;
  floatx4 accP[8], accG[8];
  #pragma unroll
  for (int i = 0; i < 8; ++i){ accP[i] = (floatx4){0,0,0,0}; accG[i] = (floatx4){0,0,0,0}; }
  #pragma unroll
  for (int s = 0; s < 10; ++s){
    short8 a = *(const short8*)(xrow + s * 32 + klane);
    #pragma unroll
    for (int cc = 0; cc < 8; ++cc){
      short8 bp = *(const short8*)(WpP + (((size_t)(cbase + cc) * 10 + s) * 64 + lane) * 8);
      accP[cc] = __builtin_amdgcn_mfma_f32_16x16x32_bf16(a, bp, accP[cc], 0, 0, 0);
      short8 bg = *(const short8*)(WgP + (((size_t)(cbase + cc) * 10 + s) * 64 + lane) * 8);
      accG[cc] = __builtin_amdgcn_mfma_f32_16x16x32_bf16(a, bg, accG[cc], 0, 0, 0);
    }
  }
  int rbase = r0 + ((lane >> 4) << 2);
  #pragma unroll
  for (int cc = 0; cc < 8; ++cc){
    int col = (cbase + cc) * 16 + (lane & 15);
    float bp = b_proj[col], bg = b_gate[col];
    #pragma unroll
    for (int r = 0; r < 4; ++r){
      int row = rbase + r;
      float cv = accP[cc][r] + bp;
      float hv = sigm(accG[cc][r] + bg) * ftanh(cv);
      size_t o = (size_t)row * H_ + col;
      leaf_c[o] = f2bf(cv);
      leaf_h[o] = f2bf(hv);
    }
  }
}

// ---------------------------------------------------------------------------
// Persistent chain, R15. Protocol = R14 exactly (agent flags on distinct
// 128B lines, role-swapped waves, distributed reduce/epilogue, two barriers).
// Three local-compute changes:
//  1. LEAF A PREFETCH one event ahead (codes precomputed in lsel/rsel):
//     issue event e+1's leaf loads into a second register buffer during
//     event e, so HBM misses hide behind a full event period instead of
//     stalling before S2 (removes the max-over-32-blocks HBM-tail term
//     that set the 6us group period).
//  2. Wreg hoisted out of the event loop (loop-invariant; was 40 b128
//     loads/event/wave).
//  3. Conflict-free LDS partials: float parts[4][2][5][4][64] scalar
//     layout, bank = lane%32 (2 lanes/bank = free). R14's floatx4 layout
//     was an 8-way conflict (1.04e7 conflict cycles).
// ---------------------------------------------------------------------------
__global__ __launch_bounds__(256, 1) void chain_kernel(
    const ushort_t* __restrict__ WrP, const float* __restrict__ b_reduce,
    const ushort_t* __restrict__ leaf_h, const ushort_t* __restrict__ leaf_c,
    ushort_t* __restrict__ slot_h, float* __restrict__ slot_c,
    const int* __restrict__ lsel, const int* __restrict__ rsel,
    const int* __restrict__ wph, const ushort_t* __restrict__ zbuf,
    unsigned* __restrict__ gflags){
  __shared__ float parts[4][2][5][4][64];                       // 40 KB, conflict-free
  __shared__ ushort_t hp[4][8][16] __attribute__((aligned(8))); // 1 KB
  const int bid  = blockIdx.x;
  const int cth  = bid >> 3;
  const int rg   = bid & 7;
  const int kq   = threadIdx.x >> 6;     // wave
  const int lane = threadIdx.x & 63;
  const int m16  = lane & 15;
  const int klane = (lane >> 4) << 3;
  const int colh = cth * 16 + m16;
  const int row0 = rg * 32;
  // role: waves 0,1 -> RIGHT child (rsel), W K-quarters 2,3 (K [512,1024))
  //       waves 2,3 -> LEFT  child (lsel), W K-quarters 0,1 (K [0,512))
  const int* ssel = (kq < 2) ? rsel : lsel;
  const int qK    = (kq < 2) ? (2 + kq) : (kq - 2);
  const int kcolbase = (kq & 1) * 256;   // col offset within child h
  float bias[5];
  #pragma unroll
  for (int g = 0; g < 5; ++g) bias[g] = b_reduce[g * H_ + colh];
  unsigned* myflag  = gflags + ((unsigned)(rg * 32 + cth) << 5);            // 128B stride
  unsigned* pollptr = gflags + ((unsigned)(rg * 32 + (kq & 1) * 16 + m16) << 5);
  const int err_ = lane >> 4;            // epilogue row sub-slot (0..3)
  float creg[2] = {0.0f, 0.0f};          // prev-event c for owned rows

  // ---- W fragments: loop-invariant; load + pin ONCE ----
  short8 Wreg[5][8];
  #pragma unroll
  for (int g = 0; g < 5; ++g)
    #pragma unroll
    for (int s = 0; s < 8; ++s)
      Wreg[g][s] = *(const short8*)(WrP + (((size_t)(g * 32 + cth) * 32 + qK * 8 + s) * 64 + lane) * 8);
  #pragma unroll
  for (int g = 0; g < 5; ++g)
    asm volatile("" : "+v"(Wreg[g][0]), "+v"(Wreg[g][1]), "+v"(Wreg[g][2]),
                      "+v"(Wreg[g][3]), "+v"(Wreg[g][4]), "+v"(Wreg[g][5]),
                      "+v"(Wreg[g][6]), "+v"(Wreg[g][7]));

  union AB { u64_t q[16]; short8 v[8]; };
  AB abc[2], abn[2];
  int code[2];

  // ---- prologue: codes + leaf A for event 0 ----
  #pragma unroll
  for (int rt = 0; rt < 2; ++rt){
    int row = row0 + rt * 16 + m16;
    code[rt] = ssel[0 * B_ + row] & 0x3FF;
    const ushort_t* lp = (code[rt] < 128) ? leaf_h + ((size_t)row * T_ + code[rt]) * H_ + kcolbase
                                          : zbuf;
    if (code[rt] < 256 || code[rt] >= 512){
      #pragma unroll
      for (int s = 0; s < 8; ++s) abc[rt].v[s] = *(const short8*)(lp + s * 32 + klane);
    }
  }

  #pragma unroll 1
  for (int e = 0; e < NE_; ++e){
    const bool isnode0 = (code[0] >= 256 && code[0] < 512);
    const bool isnode1 = (code[1] >= 256 && code[1] < 512);

    // ---- per-wave epilogue operand prefetch (owned rows: kq*8 .. kq*8+8) ----
    float cl[2], cr[2];
    int wv[2];
    #pragma unroll
    for (int rix = 0; rix < 2; ++rix){
      const int R  = kq * 8 + err_ * 2 + rix;
      const int bb = row0 + R;
      const int ls = lsel[e * B_ + bb], rs = rsel[e * B_ + bb];
      wv[rix] = wph[e * B_ + bb];
      int lc = ls & 0x3FF, rc = rs & 0x3FF;
      float lv = 0.0f, rv = 0.0f;
      if (ls & PREVF_) lv = creg[rix];
      else if (lc < 128) lv = bf2f(leaf_c[((size_t)bb * T_ + lc) * H_ + colh]);
      else if (lc < 512) lv = slot_c[((size_t)bb * SLC_ + ((lc - 256) >> 1)) * H_ + colh];
      if (rs & PREVF_) rv = creg[rix];
      else if (rc < 128) rv = bf2f(leaf_c[((size_t)bb * T_ + rc) * H_ + colh]);
      else if (rc < 512) rv = slot_c[((size_t)bb * SLC_ + ((rc - 256) >> 1)) * H_ + colh];
      cl[rix] = lv; cr[rix] = rv;
    }

    // ---- prefetch NEXT event's leaf A (codes precomputed; hides HBM) ----
    int ncode[2] = {code[0], code[1]};
    if (e + 1 < NE_){
      #pragma unroll
      for (int rt = 0; rt < 2; ++rt){
        int row = row0 + rt * 16 + m16;
        ncode[rt] = ssel[(e + 1) * B_ + row] & 0x3FF;
        const ushort_t* lp = (ncode[rt] < 128) ? leaf_h + ((size_t)row * T_ + ncode[rt]) * H_ + kcolbase
                                               : zbuf;
        if (ncode[rt] < 256 || ncode[rt] >= 512){
          #pragma unroll
          for (int s = 0; s < 8; ++s) abn[rt].v[s] = *(const short8*)(lp + s * 32 + klane);
        }
      }
    }

    // ---- pre-wait MFMA for leaf/zero rts; partials to LDS early ----
    floatx4 acc[2][5];
    #pragma unroll
    for (int rt = 0; rt < 2; ++rt)
      #pragma unroll
      for (int g = 0; g < 5; ++g) acc[rt][g] = (floatx4){0,0,0,0};
    #pragma unroll
    for (int rt = 0; rt < 2; ++rt){
      if (!(rt == 0 ? isnode0 : isnode1)){
        #pragma unroll
        for (int s = 0; s < 8; ++s)
          #pragma unroll
          for (int g = 0; g < 5; ++g)
            acc[rt][g] = __builtin_amdgcn_mfma_f32_16x16x32_bf16(abc[rt].v[s], Wreg[g][s], acc[rt][g], 0, 0, 0);
        #pragma unroll
        for (int g = 0; g < 5; ++g)
          #pragma unroll
          for (int r = 0; r < 4; ++r)
            parts[kq][rt][g][r][lane] = acc[rt][g][r];
      }
    }

    // ---- wait (only waves with a node child; 16 producer lines) ----
    if (isnode0 || isnode1){
      const unsigned tgt = (unsigned)e;
      int it = 0;
      for (;;){
        unsigned v = __hip_atomic_load(pollptr, __ATOMIC_RELAXED, __HIP_MEMORY_SCOPE_AGENT);
        if (__all(v >= tgt)) break;
        if (it < 2)       __builtin_amdgcn_s_sleep(0);
        else if (it < 16) __builtin_amdgcn_s_sleep(2);
        else              __builtin_amdgcn_s_sleep(8);
        ++it;
      }
    }

    // ---- node-child loads (batched agent 8B) + MFMA + partials ----
    #pragma unroll
    for (int rt = 0; rt < 2; ++rt){
      if (rt == 0 ? isnode0 : isnode1){
        int row = row0 + rt * 16 + m16;
        const ushort_t* p = slot_h + ((size_t)row * SLH_ + (code[rt] - 256)) * H_ + kcolbase + klane;
        #pragma unroll
        for (int s = 0; s < 8; ++s){
          abc[rt].q[2 * s]     = __hip_atomic_load((const u64_t*)(p + s * 32),
                                  __ATOMIC_RELAXED, __HIP_MEMORY_SCOPE_AGENT);
          abc[rt].q[2 * s + 1] = __hip_atomic_load((const u64_t*)(p + s * 32 + 4),
                                  __ATOMIC_RELAXED, __HIP_MEMORY_SCOPE_AGENT);
        }
        #pragma unroll
        for (int s = 0; s < 8; ++s)
          #pragma unroll
          for (int g = 0; g < 5; ++g)
            acc[rt][g] = __builtin_amdgcn_mfma_f32_16x16x32_bf16(abc[rt].v[s], Wreg[g][s], acc[rt][g], 0, 0, 0);
        #pragma unroll
        for (int g = 0; g < 5; ++g)
          #pragma unroll
          for (int r = 0; r < 4; ++r)
            parts[kq][rt][g][r][lane] = acc[rt][g][r];
      }
    }
    __syncthreads();   // S2: all partials visible

    // ---- distributed reduce + epilogue: 2 cells/lane on owned rows ----
    #pragma unroll
    for (int rix = 0; rix < 2; ++rix){
      const int R    = kq * 8 + err_ * 2 + rix;
      const int bb   = row0 + R;
      const int rt2  = R >> 4;
      const int lane2 = (((R >> 2) & 3) << 4) + m16;
      const int rsub = R & 3;
      float o[5];
      #pragma unroll
      for (int g = 0; g < 5; ++g)
        o[g] = parts[0][rt2][g][rsub][lane2] + parts[1][rt2][g][rsub][lane2]
             + parts[2][rt2][g][rsub][lane2] + parts[3][rt2][g][rsub][lane2] + bias[g];
      float cn = sigm(o[1]) * cl[rix] + sigm(o[2]) * cr[rix] + sigm(o[0]) * ftanh(o[3]);
      float hn = sigm(o[4]) * ftanh(cn);
      creg[rix] = cn;
      slot_c[((size_t)bb * SLC_ + (wv[rix] >> 1)) * H_ + colh] = cn;   // WG-private
      hp[kq][err_ * 2 + rix][m16] = f2bf(hn);
    }
    // ---- per-wave packed h store: lanes 0-31, 8B contiguous each ----
    if (lane < 32){
      int rl = lane >> 2, qw = lane & 3;
      int bb2 = row0 + kq * 8 + rl;
      int w2 = wph[e * B_ + bb2];
      ushort_t* dst = slot_h + ((size_t)bb2 * SLH_ + w2) * H_ + cth * 16 + qw * 4;
      u64_t qv = *(const u64_t*)&hp[kq][rl][qw * 4];
      store_h_coh64((u64_t*)dst, qv);
    }
    asm volatile("s_waitcnt vmcnt(0)" ::: "memory");   // drain own stores
    __syncthreads();   // S3: all waves drained; parts/hp reads done (WAR guard)
    if (threadIdx.x == 0)
      __hip_atomic_store(myflag, (unsigned)(e + 1),
                         __ATOMIC_RELAXED, __HIP_MEMORY_SCOPE_AGENT);

    // ---- roll prefetched state to current ----
    #pragma unroll
    for (int rt = 0; rt < 2; ++rt){
      if (ncode[rt] < 256 || ncode[rt] >= 512) abc[rt] = abn[rt];
      code[rt] = ncode[rt];
    }
  }
}

// Final: out[b][j] = h of root (leaf / node slot / zeros). Covers every row.
__global__ __launch_bounds__(256) void final_kernel(const int* __restrict__ rootsel,
    const ushort_t* __restrict__ leaf_h, const ushort_t* __restrict__ slot_h,
    float* __restrict__ out){
  int i = blockIdx.x * 256 + threadIdx.x;
  if (i >= B_ * H_) return;
  int b = i >> 9, j = i & (H_ - 1);
  int code = rootsel[b] & 0x3FF;
  float v = 0.0f;
  if (code < 128)      v = bf2f(leaf_h[((size_t)b * T_ + code) * H_ + j]);
  else if (code < 512) v = bf2f(slot_h[((size_t)b * SLH_ + (code - 256)) * H_ + j]);
  out[i] = v;
}

extern "C" void kernel_launch(void* const* d_in, const int* in_sizes, int n_in,
                              void* d_out, int out_size, void* d_ws, size_t ws_size,
                              hipStream_t stream){
  const float* x        = (const float*)d_in[0];
  const float* W_proj   = (const float*)d_in[1];
  const float* b_proj   = (const float*)d_in[2];
  const float* W_gate   = (const float*)d_in[3];
  const float* b_gate   = (const float*)d_in[4];
  const float* W_reduce = (const float*)d_in[5];
  const float* b_reduce = (const float*)d_in[6];
  const int*   trans    = (const int*)d_in[7];
  float* out = (float*)d_out;

  char* ws = (char*)d_ws;
  size_t o = 0;
  ushort_t* WpP    = (ushort_t*)(ws + o); o += (size_t)32*10*64*8*2;    // 0.33 MB
  ushort_t* WgP    = (ushort_t*)(ws + o); o += (size_t)32*10*64*8*2;
  ushort_t* WrP    = (ushort_t*)(ws + o); o += (size_t)160*32*64*8*2;   // 5.24 MB
  ushort_t* leaf_h = (ushort_t*)(ws + o); o += (size_t)B_*T_*H_*2;      // 33.5 MB
  ushort_t* leaf_c = (ushort_t*)(ws + o); o += (size_t)B_*T_*H_*2;      // 33.5 MB
  ushort_t* slot_h = (ushort_t*)(ws + o); o += (size_t)B_*SLH_*H_*2;    // 68.2 MB
  float*    slot_c = (float*)(ws + o);    o += (size_t)B_*SLC_*H_*4;    // 68.2 MB
  int* lsel    = (int*)(ws + o); o += (size_t)NE_*B_*4;
  int* rsel    = (int*)(ws + o); o += (size_t)NE_*B_*4;
  int* wph     = (int*)(ws + o); o += (size_t)NE_*B_*4;
  int* rootsel = (int*)(ws + o); o += (size_t)B_*4;
  unsigned* gflags = (unsigned*)(ws + o); o += (size_t)8 * 32 * 128;  // 1 line per (rg,cth)
  ushort_t* zbuf = (ushort_t*)(ws + o); o += 2048;
  // xb (bf16 x, padded to K=320, 21 MB) overlays slot_c: xb is only read
  // before chain_kernel; slot_c is only accessed during/after it.
  ushort_t* xb = (ushort_t*)slot_c;
  (void)ws_size; (void)in_sizes; (void)n_in; (void)out_size;

  hipMemsetAsync(gflags, 0, (size_t)8 * 32 * 128, stream);
  hipMemsetAsync(zbuf, 0, 2048, stream);
  xcast_kernel<<<((B_*T_)*40 + 255)/256, 256, 0, stream>>>(x, xb);
  pack_w_kernel<<<(32*10*64 + 255)/256, 256, 0, stream>>>(W_proj, WpP, 300, 512, 10, 32*10*64);
  pack_w_kernel<<<(32*10*64 + 255)/256, 256, 0, stream>>>(W_gate, WgP, 300, 512, 10, 32*10*64);
  pack_w_kernel<<<(160*32*64 + 255)/256, 256, 0, stream>>>(W_reduce, WrP, 1024, 2560, 32, 160*32*64);
  sched_kernel<<<8, 32, 0, stream>>>(trans, lsel, rsel, wph, rootsel);
  leaf_kernel<<<dim3(512, 4), 256, 0, stream>>>(xb, WpP, WgP, b_proj, b_gate, leaf_h, leaf_c);
  chain_kernel<<<256, 256, 0, stream>>>(WrP, b_reduce, leaf_h, leaf_c, slot_h, slot_c,
                                        lsel, rsel, wph, zbuf, gflags);
  final_kernel<<<(B_*H_ + 255)/256, 256, 0, stream>>>(rootsel, leaf_h, slot_h, out);
}

// Round 9
// 1123.625 us; speedup vs baseline: 1.8419x; 1.0395x over previous
//
#include <hip/hip_runtime.h>

typedef unsigned short ushort_t;
typedef unsigned long long u64_t;
typedef __attribute__((ext_vector_type(8))) short short8;
typedef __attribute__((ext_vector_type(4))) float floatx4;

#define B_ 256
#define T_ 128
#define E_ 300
#define H_ 512
#define NE_ 127   // T-1 reduce events
#define NT_ 255   // 2T-1 transitions
#define SLH_ 260  // slot_h slots per row (256 live + dump + pad)
#define SLC_ 130  // slot_c slots per row (128 live + dump + pad)
#define ZCODE_ 1023
#define PREVF_ 0x10000

__device__ inline ushort_t f2bf(float f){
  unsigned u = __builtin_bit_cast(unsigned, f);
  unsigned r = u + 0x7FFFu + ((u >> 16) & 1u);
  return (ushort_t)(r >> 16);
}
__device__ inline float bf2f(ushort_t h){
  unsigned u = ((unsigned)h) << 16;
  return __builtin_bit_cast(float, u);
}
__device__ inline float sigm(float x){ return 1.0f / (1.0f + __expf(-x)); }
// exp-based tanh: exact in the tails, ~ulp-level f32 error (<< bf16 noise).
__device__ inline float ftanh(float x){
  float e = __expf(2.0f * x);
  return 1.0f - 2.0f / (e + 1.0f);
}

__device__ inline void store_h_coh64(u64_t* p, u64_t v){
  __hip_atomic_store(p, v, __ATOMIC_RELAXED, __HIP_MEMORY_SCOPE_AGENT);
}

// ---------------------------------------------------------------------------
// x (fp32, rows of 300) -> xb (bf16, rows padded to 320, pad = 0)
// ---------------------------------------------------------------------------
__global__ __launch_bounds__(256) void xcast_kernel(const float* __restrict__ x,
    ushort_t* __restrict__ xb){
  int t = blockIdx.x * 256 + threadIdx.x;
  if (t >= (B_ * T_) * 40) return;
  int row = t / 40, k8 = (t % 40) * 8;
  const float* src = x + (size_t)row * E_;
  short8 v;
  #pragma unroll
  for (int j = 0; j < 8; ++j){
    int k = k8 + j;
    v[j] = (k < E_) ? (short)f2bf(src[k]) : (short)0;
  }
  *(short8*)(xb + (size_t)row * 320 + k8) = v;
}

// ---------------------------------------------------------------------------
// Pack a KxN row-major fp32 weight into MFMA B-fragment order (bf16).
// ---------------------------------------------------------------------------
__global__ __launch_bounds__(256) void pack_w_kernel(const float* __restrict__ W,
    ushort_t* __restrict__ dst, int K, int N, int NS, int total){
  int t = blockIdx.x * 256 + threadIdx.x;
  if (t >= total) return;
  int L = t & 63;
  int s = (t >> 6) % NS;
  int ct = t / (64 * NS);
  int n = ct * 16 + (L & 15);
  int kbase = s * 32 + ((L >> 4) << 3);
  short8 pack;
  #pragma unroll
  for (int j = 0; j < 8; ++j){
    int k = kbase + j;
    pack[j] = (k < K) ? (short)f2bf(W[(size_t)k * N + n]) : (short)0;
  }
  *(short8*)(dst + (size_t)t * 8) = pack;
}

// ---------------------------------------------------------------------------
// Stack machine with SLOT-RECYCLED storage. Codes (low 10 bits):
//   [0,128) leaf | [256,512) node at phys h-slot (c-slot = phys>>1) | 1023 zeros
// PREVF_: child is the previous event's node (c register-carried).
// R16: transitions prefetched in 8-wide static-index batches — the serial
// loop previously stalled ~400ns per iteration on a dependent global load
// (255 iters ~ 100us). Batched loads pipeline 8 deep.
// ---------------------------------------------------------------------------
__global__ void sched_kernel(const int* __restrict__ trans, int* __restrict__ lsel,
    int* __restrict__ rsel, int* __restrict__ wph, int* __restrict__ rootsel){
  __shared__ int stk[32 * 128];    // value code
  __shared__ int stkid[32 * 128];  // node id (T_+e) or leaf idx
  int tid = threadIdx.x;           // 0..31
  int b0 = blockIdx.x * 32;
  int b = b0 + tid;
  for (int i = 0; i < 128; ++i){ stk[tid * 128 + i] = ZCODE_; stkid[tid * 128 + i] = -1; }
  u64_t tog0 = 0, tog1 = 0;
  int sp = 0, bp = T_, e = 0;
  for (int t0 = 0; t0 < NT_; t0 += 8){
    int trv[8];
    #pragma unroll
    for (int i = 0; i < 8; ++i){
      int t = t0 + i;
      trv[i] = (t < NT_) ? trans[t * B_ + b] : 1;
    }
    #pragma unroll
    for (int i = 0; i < 8; ++i){
      int t = t0 + i;
      if (t < NT_){
        int tr = trv[i];
        if (tr == 0){
          int pos = sp; if (pos < 0) pos = 0; if (pos > 127) pos = 127;
          stk[tid * 128 + pos] = bp - 1;
          stkid[tid * 128 + pos] = bp - 1;
          sp += 1; bp -= 1;
        } else {
          int i2 = sp - 2; if (i2 < 0) i2 = 0; if (i2 > 127) i2 = 127;
          int i1 = sp - 1; if (i1 < 0) i1 = 0; if (i1 > 127) i1 = 127;
          if (e < NE_){
            int lc = stk[tid * 128 + i2], rc = stk[tid * 128 + i1];
            int lid = stkid[tid * 128 + i2], rid = stkid[tid * 128 + i1];
            int previd = T_ + e - 1;
            lsel[e * B_ + b] = lc | ((e > 0 && lid == previd) ? PREVF_ : 0);
            rsel[e * B_ + b] = rc | ((e > 0 && rid == previd) ? PREVF_ : 0);
            int pos = i2;
            unsigned ob;
            if (pos < 64){ ob = (unsigned)((tog0 >> pos) & 1); tog0 ^= (1ull << pos); }
            else         { ob = (unsigned)((tog1 >> (pos - 64)) & 1); tog1 ^= (1ull << (pos - 64)); }
            int phys = pos * 2 + (int)(ob ^ 1u);
            wph[e * B_ + b] = phys;
            stk[tid * 128 + pos] = 256 + phys;
            stkid[tid * 128 + pos] = T_ + e;
          }
          e += 1; sp -= 1;
        }
      }
    }
  }
  for (int k = e; k < NE_; ++k){
    lsel[k * B_ + b] = ZCODE_; rsel[k * B_ + b] = ZCODE_;
    wph[k * B_ + b] = 256;     // dump slot — never aliases live slots
  }
  int ip = sp - 1; if (ip < 0) ip = 0; if (ip > 127) ip = 127;
  rootsel[b] = stk[tid * 128 + ip];
}

// ---------------------------------------------------------------------------
// Leaf phase from pre-cast bf16 x (padded K=320). WG = 4 waves x 16 rows =
// 64 rows, 128 cols (8 col-tiles) for both weights. Grid (512, 4).
// ---------------------------------------------------------------------------
__global__ __launch_bounds__(256) void leaf_kernel(const ushort_t* __restrict__ xb,
    const ushort_t* __restrict__ WpP, const ushort_t* __restrict__ WgP,
    const float* __restrict__ b_proj, const float* __restrict__ b_gate,
    ushort_t* __restrict__ leaf_h, ushort_t* __restrict__ leaf_c){
  int wave = threadIdx.x >> 6, lane = threadIdx.x & 63;
  int r0 = blockIdx.x * 64 + wave * 16;
  int cbase = blockIdx.y * 8;
  int arow = r0 + (lane & 15);
  int klane = (lane >> 4) << 3;
  const ushort_t* xrow = xb + (size_t)arow * 320;
  floatx4 accP[8], accG[8];
  #pragma unroll
  for (int i = 0; i < 8; ++i){ accP[i] = (floatx4){0,0,0,0}; accG[i] = (floatx4){0,0,0,0}; }
  #pragma unroll
  for (int s = 0; s < 10; ++s){
    short8 a = *(const short8*)(xrow + s * 32 + klane);
    #pragma unroll
    for (int cc = 0; cc < 8; ++cc){
      short8 bp = *(const short8*)(WpP + (((size_t)(cbase + cc) * 10 + s) * 64 + lane) * 8);
      accP[cc] = __builtin_amdgcn_mfma_f32_16x16x32_bf16(a, bp, accP[cc], 0, 0, 0);
      short8 bg = *(const short8*)(WgP + (((size_t)(cbase + cc) * 10 + s) * 64 + lane) * 8);
      accG[cc] = __builtin_amdgcn_mfma_f32_16x16x32_bf16(a, bg, accG[cc], 0, 0, 0);
    }
  }
  int rbase = r0 + ((lane >> 4) << 2);
  #pragma unroll
  for (int cc = 0; cc < 8; ++cc){
    int col = (cbase + cc) * 16 + (lane & 15);
    float bp = b_proj[col], bg = b_gate[col];
    #pragma unroll
    for (int r = 0; r < 4; ++r){
      int row = rbase + r;
      float cv = accP[cc][r] + bp;
      float hv = sigm(accG[cc][r] + bg) * ftanh(cv);
      size_t o = (size_t)row * H_ + col;
      leaf_c[o] = f2bf(cv);
      leaf_h[o] = f2bf(hv);
    }
  }
}

// ---------------------------------------------------------------------------
// Persistent chain, R16. Structure = R15 (role-swapped waves, distributed
// reduce/epilogue, leaf prefetch, hoisted Wreg, conflict-free parts).
// Handoff-latency cuts (R15 post-mortem: period ⊥ local work — it's the
// agent-RT chain + wake/convoy overhead):
//  1. BUSY-POLL (no s_sleep): poll iteration = one HBM RT (~400ns); the
//     escalating backoff added up to ~500cy wake quantization per event.
//  2. EARLY FLAG: each wave drains its OWN h stores then bumps an LDS
//     counter; the LAST wave stores the agent flag immediately — removes
//     the S3 barrier + thread0 rendezvous from the flag path. S3 retained
//     after (WAR guard for parts/hp only).
// ---------------------------------------------------------------------------
__global__ __launch_bounds__(256, 1) void chain_kernel(
    const ushort_t* __restrict__ WrP, const float* __restrict__ b_reduce,
    const ushort_t* __restrict__ leaf_h, const ushort_t* __restrict__ leaf_c,
    ushort_t* __restrict__ slot_h, float* __restrict__ slot_c,
    const int* __restrict__ lsel, const int* __restrict__ rsel,
    const int* __restrict__ wph, const ushort_t* __restrict__ zbuf,
    unsigned* __restrict__ gflags){
  __shared__ float parts[4][2][5][4][64];                       // 40 KB, conflict-free
  __shared__ ushort_t hp[4][8][16] __attribute__((aligned(8))); // 1 KB
  __shared__ int done_ctr;                                      // early-flag counter
  const int bid  = blockIdx.x;
  const int cth  = bid >> 3;
  const int rg   = bid & 7;
  const int kq   = threadIdx.x >> 6;     // wave
  const int lane = threadIdx.x & 63;
  const int m16  = lane & 15;
  const int klane = (lane >> 4) << 3;
  const int colh = cth * 16 + m16;
  const int row0 = rg * 32;
  if (threadIdx.x == 0) done_ctr = 0;
  // role: waves 0,1 -> RIGHT child (rsel), W K-quarters 2,3 (K [512,1024))
  //       waves 2,3 -> LEFT  child (lsel), W K-quarters 0,1 (K [0,512))
  const int* ssel = (kq < 2) ? rsel : lsel;
  const int qK    = (kq < 2) ? (2 + kq) : (kq - 2);
  const int kcolbase = (kq & 1) * 256;   // col offset within child h
  float bias[5];
  #pragma unroll
  for (int g = 0; g < 5; ++g) bias[g] = b_reduce[g * H_ + colh];
  unsigned* myflag  = gflags + ((unsigned)(rg * 32 + cth) << 5);            // 128B stride
  unsigned* pollptr = gflags + ((unsigned)(rg * 32 + (kq & 1) * 16 + m16) << 5);
  const int err_ = lane >> 4;            // epilogue row sub-slot (0..3)
  float creg[2] = {0.0f, 0.0f};          // prev-event c for owned rows

  // ---- W fragments: loop-invariant; load + pin ONCE ----
  short8 Wreg[5][8];
  #pragma unroll
  for (int g = 0; g < 5; ++g)
    #pragma unroll
    for (int s = 0; s < 8; ++s)
      Wreg[g][s] = *(const short8*)(WrP + (((size_t)(g * 32 + cth) * 32 + qK * 8 + s) * 64 + lane) * 8);
  #pragma unroll
  for (int g = 0; g < 5; ++g)
    asm volatile("" : "+v"(Wreg[g][0]), "+v"(Wreg[g][1]), "+v"(Wreg[g][2]),
                      "+v"(Wreg[g][3]), "+v"(Wreg[g][4]), "+v"(Wreg[g][5]),
                      "+v"(Wreg[g][6]), "+v"(Wreg[g][7]));

  union AB { u64_t q[16]; short8 v[8]; };
  AB abc[2], abn[2];
  int code[2];

  // ---- prologue: codes + leaf A for event 0 ----
  #pragma unroll
  for (int rt = 0; rt < 2; ++rt){
    int row = row0 + rt * 16 + m16;
    code[rt] = ssel[0 * B_ + row] & 0x3FF;
    const ushort_t* lp = (code[rt] < 128) ? leaf_h + ((size_t)row * T_ + code[rt]) * H_ + kcolbase
                                          : zbuf;
    if (code[rt] < 256 || code[rt] >= 512){
      #pragma unroll
      for (int s = 0; s < 8; ++s) abc[rt].v[s] = *(const short8*)(lp + s * 32 + klane);
    }
  }

  #pragma unroll 1
  for (int e = 0; e < NE_; ++e){
    const bool isnode0 = (code[0] >= 256 && code[0] < 512);
    const bool isnode1 = (code[1] >= 256 && code[1] < 512);

    // ---- per-wave epilogue operand prefetch (owned rows: kq*8 .. kq*8+8) ----
    float cl[2], cr[2];
    int wv[2];
    #pragma unroll
    for (int rix = 0; rix < 2; ++rix){
      const int R  = kq * 8 + err_ * 2 + rix;
      const int bb = row0 + R;
      const int ls = lsel[e * B_ + bb], rs = rsel[e * B_ + bb];
      wv[rix] = wph[e * B_ + bb];
      int lc = ls & 0x3FF, rc = rs & 0x3FF;
      float lv = 0.0f, rv = 0.0f;
      if (ls & PREVF_) lv = creg[rix];
      else if (lc < 128) lv = bf2f(leaf_c[((size_t)bb * T_ + lc) * H_ + colh]);
      else if (lc < 512) lv = slot_c[((size_t)bb * SLC_ + ((lc - 256) >> 1)) * H_ + colh];
      if (rs & PREVF_) rv = creg[rix];
      else if (rc < 128) rv = bf2f(leaf_c[((size_t)bb * T_ + rc) * H_ + colh]);
      else if (rc < 512) rv = slot_c[((size_t)bb * SLC_ + ((rc - 256) >> 1)) * H_ + colh];
      cl[rix] = lv; cr[rix] = rv;
    }

    // ---- prefetch NEXT event's leaf A (codes precomputed; hides HBM) ----
    int ncode[2] = {code[0], code[1]};
    if (e + 1 < NE_){
      #pragma unroll
      for (int rt = 0; rt < 2; ++rt){
        int row = row0 + rt * 16 + m16;
        ncode[rt] = ssel[(e + 1) * B_ + row] & 0x3FF;
        const ushort_t* lp = (ncode[rt] < 128) ? leaf_h + ((size_t)row * T_ + ncode[rt]) * H_ + kcolbase
                                               : zbuf;
        if (ncode[rt] < 256 || ncode[rt] >= 512){
          #pragma unroll
          for (int s = 0; s < 8; ++s) abn[rt].v[s] = *(const short8*)(lp + s * 32 + klane);
        }
      }
    }

    // ---- pre-wait MFMA for leaf/zero rts; partials to LDS early ----
    floatx4 acc[2][5];
    #pragma unroll
    for (int rt = 0; rt < 2; ++rt)
      #pragma unroll
      for (int g = 0; g < 5; ++g) acc[rt][g] = (floatx4){0,0,0,0};
    #pragma unroll
    for (int rt = 0; rt < 2; ++rt){
      if (!(rt == 0 ? isnode0 : isnode1)){
        #pragma unroll
        for (int s = 0; s < 8; ++s)
          #pragma unroll
          for (int g = 0; g < 5; ++g)
            acc[rt][g] = __builtin_amdgcn_mfma_f32_16x16x32_bf16(abc[rt].v[s], Wreg[g][s], acc[rt][g], 0, 0, 0);
        #pragma unroll
        for (int g = 0; g < 5; ++g)
          #pragma unroll
          for (int r = 0; r < 4; ++r)
            parts[kq][rt][g][r][lane] = acc[rt][g][r];
      }
    }

    // ---- wait (only waves with a node child): busy-spin, no sleep ----
    if (isnode0 || isnode1){
      const unsigned tgt = (unsigned)e;
      for (;;){
        unsigned v = __hip_atomic_load(pollptr, __ATOMIC_RELAXED, __HIP_MEMORY_SCOPE_AGENT);
        if (__all(v >= tgt)) break;
      }
    }

    // ---- node-child loads (batched agent 8B) + MFMA + partials ----
    #pragma unroll
    for (int rt = 0; rt < 2; ++rt){
      if (rt == 0 ? isnode0 : isnode1){
        int row = row0 + rt * 16 + m16;
        const ushort_t* p = slot_h + ((size_t)row * SLH_ + (code[rt] - 256)) * H_ + kcolbase + klane;
        #pragma unroll
        for (int s = 0; s < 8; ++s){
          abc[rt].q[2 * s]     = __hip_atomic_load((const u64_t*)(p + s * 32),
                                  __ATOMIC_RELAXED, __HIP_MEMORY_SCOPE_AGENT);
          abc[rt].q[2 * s + 1] = __hip_atomic_load((const u64_t*)(p + s * 32 + 4),
                                  __ATOMIC_RELAXED, __HIP_MEMORY_SCOPE_AGENT);
        }
        #pragma unroll
        for (int s = 0; s < 8; ++s)
          #pragma unroll
          for (int g = 0; g < 5; ++g)
            acc[rt][g] = __builtin_amdgcn_mfma_f32_16x16x32_bf16(abc[rt].v[s], Wreg[g][s], acc[rt][g], 0, 0, 0);
        #pragma unroll
        for (int g = 0; g < 5; ++g)
          #pragma unroll
          for (int r = 0; r < 4; ++r)
            parts[kq][rt][g][r][lane] = acc[rt][g][r];
      }
    }
    __syncthreads();   // S2: all partials visible

    // ---- distributed reduce + epilogue: 2 cells/lane on owned rows ----
    #pragma unroll
    for (int rix = 0; rix < 2; ++rix){
      const int R    = kq * 8 + err_ * 2 + rix;
      const int bb   = row0 + R;
      const int rt2  = R >> 4;
      const int lane2 = (((R >> 2) & 3) << 4) + m16;
      const int rsub = R & 3;
      float o[5];
      #pragma unroll
      for (int g = 0; g < 5; ++g)
        o[g] = parts[0][rt2][g][rsub][lane2] + parts[1][rt2][g][rsub][lane2]
             + parts[2][rt2][g][rsub][lane2] + parts[3][rt2][g][rsub][lane2] + bias[g];
      float cn = sigm(o[1]) * cl[rix] + sigm(o[2]) * cr[rix] + sigm(o[0]) * ftanh(o[3]);
      float hn = sigm(o[4]) * ftanh(cn);
      creg[rix] = cn;
      slot_c[((size_t)bb * SLC_ + (wv[rix] >> 1)) * H_ + colh] = cn;   // WG-private
      hp[kq][err_ * 2 + rix][m16] = f2bf(hn);
    }
    // ---- per-wave packed h store: lanes 0-31, 8B contiguous each ----
    if (lane < 32){
      int rl = lane >> 2, qw = lane & 3;
      int bb2 = row0 + kq * 8 + rl;
      int w2 = wph[e * B_ + bb2];
      ushort_t* dst = slot_h + ((size_t)bb2 * SLH_ + w2) * H_ + cth * 16 + qw * 4;
      u64_t qv = *(const u64_t*)&hp[kq][rl][qw * 4];
      store_h_coh64((u64_t*)dst, qv);
    }
    asm volatile("s_waitcnt vmcnt(0)" ::: "memory");   // drain own stores
    // ---- early flag: last-drained wave publishes (before S3) ----
    if (lane == 0){
      int prev = atomicAdd(&done_ctr, 1);
      if (prev == 4 * e + 3)
        __hip_atomic_store(myflag, (unsigned)(e + 1),
                           __ATOMIC_RELAXED, __HIP_MEMORY_SCOPE_AGENT);
    }
    __syncthreads();   // S3: WAR guard for parts/hp reuse next event

    // ---- roll prefetched state to current ----
    #pragma unroll
    for (int rt = 0; rt < 2; ++rt){
      if (ncode[rt] < 256 || ncode[rt] >= 512) abc[rt] = abn[rt];
      code[rt] = ncode[rt];
    }
  }
}

// Final: out[b][j] = h of root (leaf / node slot / zeros). Covers every row.
__global__ __launch_bounds__(256) void final_kernel(const int* __restrict__ rootsel,
    const ushort_t* __restrict__ leaf_h, const ushort_t* __restrict__ slot_h,
    float* __restrict__ out){
  int i = blockIdx.x * 256 + threadIdx.x;
  if (i >= B_ * H_) return;
  int b = i >> 9, j = i & (H_ - 1);
  int code = rootsel[b] & 0x3FF;
  float v = 0.0f;
  if (code < 128)      v = bf2f(leaf_h[((size_t)b * T_ + code) * H_ + j]);
  else if (code < 512) v = bf2f(slot_h[((size_t)b * SLH_ + (code - 256)) * H_ + j]);
  out[i] = v;
}

extern "C" void kernel_launch(void* const* d_in, const int* in_sizes, int n_in,
                              void* d_out, int out_size, void* d_ws, size_t ws_size,
                              hipStream_t stream){
  const float* x        = (const float*)d_in[0];
  const float* W_proj   = (const float*)d_in[1];
  const float* b_proj   = (const float*)d_in[2];
  const float* W_gate   = (const float*)d_in[3];
  const float* b_gate   = (const float*)d_in[4];
  const float* W_reduce = (const float*)d_in[5];
  const float* b_reduce = (const float*)d_in[6];
  const int*   trans    = (const int*)d_in[7];
  float* out = (float*)d_out;

  char* ws = (char*)d_ws;
  size_t o = 0;
  ushort_t* WpP    = (ushort_t*)(ws + o); o += (size_t)32*10*64*8*2;    // 0.33 MB
  ushort_t* WgP    = (ushort_t*)(ws + o); o += (size_t)32*10*64*8*2;
  ushort_t* WrP    = (ushort_t*)(ws + o); o += (size_t)160*32*64*8*2;   // 5.24 MB
  ushort_t* leaf_h = (ushort_t*)(ws + o); o += (size_t)B_*T_*H_*2;      // 33.5 MB
  ushort_t* leaf_c = (ushort_t*)(ws + o); o += (size_t)B_*T_*H_*2;      // 33.5 MB
  ushort_t* slot_h = (ushort_t*)(ws + o); o += (size_t)B_*SLH_*H_*2;    // 68.2 MB
  float*    slot_c = (float*)(ws + o);    o += (size_t)B_*SLC_*H_*4;    // 68.2 MB
  int* lsel    = (int*)(ws + o); o += (size_t)NE_*B_*4;
  int* rsel    = (int*)(ws + o); o += (size_t)NE_*B_*4;
  int* wph     = (int*)(ws + o); o += (size_t)NE_*B_*4;
  int* rootsel = (int*)(ws + o); o += (size_t)B_*4;
  unsigned* gflags = (unsigned*)(ws + o); o += (size_t)8 * 32 * 128;  // 1 line per (rg,cth)
  ushort_t* zbuf = (ushort_t*)(ws + o); o += 2048;
  // xb (bf16 x, padded to K=320, 21 MB) overlays slot_c: xb is only read
  // before chain_kernel; slot_c is only accessed during/after it.
  ushort_t* xb = (ushort_t*)slot_c;
  (void)ws_size; (void)in_sizes; (void)n_in; (void)out_size;

  hipMemsetAsync(gflags, 0, (size_t)8 * 32 * 128, stream);
  hipMemsetAsync(zbuf, 0, 2048, stream);
  xcast_kernel<<<((B_*T_)*40 + 255)/256, 256, 0, stream>>>(x, xb);
  pack_w_kernel<<<(32*10*64 + 255)/256, 256, 0, stream>>>(W_proj, WpP, 300, 512, 10, 32*10*64);
  pack_w_kernel<<<(32*10*64 + 255)/256, 256, 0, stream>>>(W_gate, WgP, 300, 512, 10, 32*10*64);
  pack_w_kernel<<<(160*32*64 + 255)/256, 256, 0, stream>>>(W_reduce, WrP, 1024, 2560, 32, 160*32*64);
  sched_kernel<<<8, 32, 0, stream>>>(trans, lsel, rsel, wph, rootsel);
  leaf_kernel<<<dim3(512, 4), 256, 0, stream>>>(xb, WpP, WgP, b_proj, b_gate, leaf_h, leaf_c);
  chain_kernel<<<256, 256, 0, stream>>>(WrP, b_reduce, leaf_h, leaf_c, slot_h, slot_c,
                                        lsel, rsel, wph, zbuf, gflags);
  final_kernel<<<(B_*H_ + 255)/256, 256, 0, stream>>>(rootsel, leaf_h, slot_h, out);
}